// Round 14
// baseline (358.573 us; speedup 1.0000x reference)
//
#include <hip/hip_runtime.h>
#include <hip/hip_bf16.h>

#define N_NODES 200000
#define N_EDGES 300000
#define N_Q     128
#define N_ENT   50000
#define D       256
#define DSM     64
#define SDIM    128
#define SSM     32

#define NODE_TILES 6250
#define REL_TILES  9375
#define NW_NODE    1024
#define NW_REL     1536
#define GRID_GROUPS 512

typedef __attribute__((ext_vector_type(8))) short bf16x8;
typedef __attribute__((ext_vector_type(4))) float f32x4;

__device__ __forceinline__ float leaky(float x){ return x > 0.f ? x : 0.01f*x; }

__device__ __forceinline__ unsigned short f2bf(float f){
  __hip_bfloat16 h = __float2bfloat16(f);
  return *reinterpret_cast<unsigned short*>(&h);
}
__device__ __forceinline__ unsigned pk2bf(float a, float b){
  float2 t; t.x = a; t.y = b;
  __hip_bfloat162 h = __float22bfloat162_rn(t);
  return *reinterpret_cast<unsigned*>(&h);
}
__device__ __forceinline__ float bf2f(unsigned short h){
  return __uint_as_float(((unsigned)h) << 16);
}

// pack fp32 [K][N] row-major -> bf16 MFMA B-fragment order.
__device__ __forceinline__ void dev_pack(const float* __restrict__ src,
                                         unsigned short* __restrict__ dst,
                                         int K, int N, int id, int total){
  if (id >= total) return;
  int lane = id & 63, fb = id >> 6;
  int KB = K >> 5;
  int kb = fb % KB, nb = fb / KB;
  int k0 = kb*32 + ((lane>>4)<<3);
  int n  = nb*16 + (lane & 15);
  #pragma unroll
  for (int i = 0; i < 8; ++i) dst[(size_t)id*8 + i] = f2bf(src[(size_t)(k0+i)*N + n]);
}

// ---------------- fused setup stage 1 ----------------
__global__ void k_setup1(float* out, float* denom,
                         const float* __restrict__ Wp, const float* __restrict__ Wl,
                         const float* __restrict__ Wr, float* Wnlr, float* Wrlr,
                         const float* __restrict__ bp, float* cv,
                         const float* __restrict__ qsrc, const float* __restrict__ Ws,
                         const float* __restrict__ bs, const float* __restrict__ qrel,
                         float* qs, float* qr,
                         const float* __restrict__ Wbs, unsigned short* Wbs_pk,
                         const float* __restrict__ Wc, unsigned short* Wc_pk){
  int b = blockIdx.x, tid = threadIdx.x;
  if (b < 782){
    int id = b*256 + tid;
    if (id < N_ENT) out[id] = 0.f;
    if (id < N_NODES) denom[id] = 0.f;
  } else if (b < 1038){
    int id = (b-782)*256 + tid;
    int m = id >> 14, rem = id & 16383, k = rem >> 6, c = rem & 63;
    const float* Wsrc = (m & 1) ? Wr : Wl;
    int roff = (m >> 1) * 64;
    float s = 0.f;
    for (int i = 0; i < 64; ++i) s += Wp[k*64+i] * Wsrc[(roff+i)*64 + c];
    float* o = (m >> 1) ? Wrlr : Wnlr;
    o[k*128 + (m&1)*64 + c] = s;
  } else if (b == 1038){
    int m = tid >> 6, c = tid & 63;
    const float* Wsrc = (m & 1) ? Wr : Wl;
    int roff = (m >> 1) * 64;
    float s = 0.f;
    for (int i = 0; i < 64; ++i) s += bp[i] * Wsrc[(roff+i)*64 + c];
    cv[tid] = s;
  } else if (b < 1087){
    int id = (b-1039)*256 + tid;
    if (id < N_Q*SSM){
      int q = id >> 5, i = id & 31;
      float s = bs[i];
      for (int j = 0; j < SDIM; ++j) s += qsrc[q*SDIM+j] * Ws[j*SSM+i];
      qs[id] = s;
    } else {
      int id2 = id - N_Q*SSM;
      int q = id2 >> 6, i = id2 & 63;
      float s = bp[i];
      for (int j = 0; j < D; ++j) s += qrel[q*D+j] * Wp[j*DSM+i];
      qr[id2] = s;
    }
  } else if (b < 1119){
    dev_pack(Wbs, Wbs_pk, 256, 256, (b-1087)*256 + tid, 8192);
  } else {
    dev_pack(Wc, Wc_pk, 64, 64, (b-1119)*256 + tid, 512);
  }
}

// ---------------- fused setup stage 2 ----------------
__global__ void k_setup2(const float* __restrict__ qs, const float* __restrict__ qr,
                         const float* __restrict__ Wl, const float* __restrict__ bl,
                         const float* __restrict__ Wr, const float* __restrict__ br,
                         unsigned* qctx_p,
                         const float* __restrict__ Wnlr, unsigned short* Wn_pk,
                         const float* __restrict__ Wrlr, unsigned short* Wr_pk){
  int b = blockIdx.x, tid = threadIdx.x;
  if (b < 32){
    int id = b*256 + tid;                 // 8192 = 128q * 64c
    int q = id >> 6, c = id & 63;
    float sl = bl[c], sr = br[c];
    for (int i = 0; i < SSM; ++i){
      float v = qs[q*SSM+i];
      sl += v * Wl[(128+i)*64+c];
      sr += v * Wr[(128+i)*64+c];
    }
    for (int i = 0; i < DSM; ++i){
      float v = qr[q*DSM+i];
      sl += v * Wl[(160+i)*64+c];
      sr += v * Wr[(160+i)*64+c];
    }
    qctx_p[id] = pk2bf(sl, sr);
  } else if (b < 48){
    dev_pack(Wnlr, Wn_pk, 256, 128, (b-32)*256 + tid, 4096);
  } else {
    dev_pack(Wrlr, Wr_pk, 256, 128, (b-48)*256 + tid, 4096);
  }
}

// ---------------- persistent fused projection kernel ----------------
// 2560 persistent blocks (10/CU at 16KB LDS): groups of 5 = 2 node workers +
// 3 rel workers. Each worker loops over ~6 tiles (stride NW_*). Block launch /
// drain overhead is gone; stores of tile t overlap staging of tile t+1 across
// the 10 co-resident blocks. Tile body identical to R12 (64 VGPR, proven).
__global__ __launch_bounds__(256) void k_proj(const float* __restrict__ A,
    const unsigned short* __restrict__ Wbs_pk, const float* __restrict__ bbs,
    const unsigned short* __restrict__ Wn_pk, const float* __restrict__ cv,
    unsigned short* __restrict__ node_l, unsigned short* __restrict__ node_r,
    const float* __restrict__ relE, const unsigned short* __restrict__ Wr_pk,
    unsigned* __restrict__ rel_pk){
  __shared__ char smem[16384];
  int tid = threadIdx.x;
  int l = tid & 63, wn = tid >> 6;
  int g = blockIdx.x / 5, r5 = blockIdx.x % 5;

  if (r5 < 2){
    // ================= node worker =================
    int w = g*2 + r5;                     // [0, NW_NODE)
    for (int t = w; t < NODE_TILES; t += NW_NODE){
      int row0 = t * 32;
      {
        const float4* Ag = (const float4*)(A + (size_t)row0 * 256);
        #pragma unroll
        for (int it = 0; it < 8; ++it){
          int f = tid + 256*it;
          int r = f >> 6, c4 = f & 63;
          float4 v = Ag[f];
          uint2 u;
          u.x = pk2bf(v.x, v.y);
          u.y = pk2bf(v.z, v.w);
          int byte = (r << 9) + (c4 << 3);
          byte ^= (r & 7) << 4;
          *(uint2*)(smem + byte) = u;
        }
      }
      __syncthreads();
      f32x4 acc[2][4];
      #pragma unroll
      for (int mf = 0; mf < 2; ++mf)
        #pragma unroll
        for (int nf = 0; nf < 4; ++nf) acc[mf][nf] = (f32x4){0.f,0.f,0.f,0.f};
      for (int kb = 0; kb < 8; ++kb){
        bf16x8 a[2], b[4];
        #pragma unroll
        for (int mf = 0; mf < 2; ++mf){
          int row = mf*16 + (l & 15);
          int byte = (row << 9) + kb*64 + ((l >> 4) << 4);
          byte ^= (row & 7) << 4;
          a[mf] = *(const bf16x8*)(smem + byte);
        }
        #pragma unroll
        for (int nf = 0; nf < 4; ++nf){
          int nbb = wn*4 + nf;
          b[nf] = *(const bf16x8*)(Wbs_pk + ((size_t)(nbb*8 + kb)*64 + l)*8);
        }
        #pragma unroll
        for (int mf = 0; mf < 2; ++mf)
          #pragma unroll
          for (int nf = 0; nf < 4; ++nf)
            acc[mf][nf] = __builtin_amdgcn_mfma_f32_16x16x32_bf16(a[mf], b[nf], acc[mf][nf], 0, 0, 0);
      }
      __syncthreads();
      #pragma unroll
      for (int mf = 0; mf < 2; ++mf)
        #pragma unroll
        for (int nf = 0; nf < 4; ++nf){
          int col = wn*64 + nf*16 + (l & 15);
          float bb = bbs[col];
          #pragma unroll
          for (int r = 0; r < 4; ++r){
            int row = mf*16 + ((l >> 4) << 2) + r;
            int byte = (row << 9) + col*2;
            byte ^= (row & 7) << 4;
            *(unsigned short*)(smem + byte) = f2bf(leaky(acc[mf][nf][r] + bb));
          }
        }
      __syncthreads();
      f32x4 acc2[2][2];
      #pragma unroll
      for (int mf = 0; mf < 2; ++mf){ acc2[mf][0] = (f32x4){0.f,0.f,0.f,0.f}; acc2[mf][1] = (f32x4){0.f,0.f,0.f,0.f}; }
      for (int kb = 0; kb < 8; ++kb){
        bf16x8 a[2], b[2];
        #pragma unroll
        for (int mf = 0; mf < 2; ++mf){
          int row = mf*16 + (l & 15);
          int byte = (row << 9) + kb*64 + ((l >> 4) << 4);
          byte ^= (row & 7) << 4;
          a[mf] = *(const bf16x8*)(smem + byte);
        }
        #pragma unroll
        for (int nf = 0; nf < 2; ++nf){
          int nbb = wn*2 + nf;
          b[nf] = *(const bf16x8*)(Wn_pk + ((size_t)(nbb*8 + kb)*64 + l)*8);
        }
        #pragma unroll
        for (int mf = 0; mf < 2; ++mf)
          #pragma unroll
          for (int nf = 0; nf < 2; ++nf)
            acc2[mf][nf] = __builtin_amdgcn_mfma_f32_16x16x32_bf16(a[mf], b[nf], acc2[mf][nf], 0, 0, 0);
      }
      #pragma unroll
      for (int mf = 0; mf < 2; ++mf)
        #pragma unroll
        for (int nf = 0; nf < 2; ++nf){
          int col = wn*32 + nf*16 + (l & 15);
          float cc = cv[col];
          #pragma unroll
          for (int r = 0; r < 4; ++r){
            int row = mf*16 + ((l >> 4) << 2) + r;
            unsigned short h = f2bf(acc2[mf][nf][r] + cc);
            size_t gg = (size_t)(row0 + row);
            if (col < 64) node_l[gg*64 + col] = h;
            else          node_r[gg*64 + col - 64] = h;
          }
        }
      __syncthreads();   // phase2 LDS reads complete before next stage overwrites
    }
  } else {
    // ================= rel worker =================
    int w = g*3 + (r5 - 2);               // [0, NW_REL)
    for (int t = w; t < REL_TILES; t += NW_REL){
      int row0 = t * 32;
      {
        const float4* Rg = (const float4*)(relE + (size_t)row0 * 256);
        #pragma unroll
        for (int it = 0; it < 8; ++it){
          int f = tid + 256*it;
          int r = f >> 6, c4 = f & 63;
          float4 v = Rg[f];
          uint2 u;
          u.x = pk2bf(v.x, v.y);
          u.y = pk2bf(v.z, v.w);
          int byte = (r << 9) + (c4 << 3);
          byte ^= (r & 7) << 4;
          *(uint2*)(smem + byte) = u;
        }
      }
      __syncthreads();
      f32x4 acc[2][2];
      #pragma unroll
      for (int mf = 0; mf < 2; ++mf){ acc[mf][0] = (f32x4){0.f,0.f,0.f,0.f}; acc[mf][1] = (f32x4){0.f,0.f,0.f,0.f}; }
      for (int kb = 0; kb < 8; ++kb){
        bf16x8 a[2], b0, b1;
        #pragma unroll
        for (int mf = 0; mf < 2; ++mf){
          int row = mf*16 + (l & 15);
          int byte = (row << 9) + kb*64 + ((l >> 4) << 4);
          byte ^= (row & 7) << 4;
          a[mf] = *(const bf16x8*)(smem + byte);
        }
        b0 = *(const bf16x8*)(Wr_pk + ((size_t)(wn*8 + kb)*64 + l)*8);        // left  nb=wn
        b1 = *(const bf16x8*)(Wr_pk + ((size_t)((4+wn)*8 + kb)*64 + l)*8);    // right nb=4+wn
        #pragma unroll
        for (int mf = 0; mf < 2; ++mf){
          acc[mf][0] = __builtin_amdgcn_mfma_f32_16x16x32_bf16(a[mf], b0, acc[mf][0], 0, 0, 0);
          acc[mf][1] = __builtin_amdgcn_mfma_f32_16x16x32_bf16(a[mf], b1, acc[mf][1], 0, 0, 0);
        }
      }
      int c = wn*16 + (l & 15);
      float cvL = cv[128 + c], cvR = cv[192 + c];
      #pragma unroll
      for (int mf = 0; mf < 2; ++mf)
        #pragma unroll
        for (int r = 0; r < 4; ++r){
          int row = mf*16 + ((l >> 4) << 2) + r;
          rel_pk[(size_t)(row0 + row)*64 + c] = pk2bf(acc[mf][0][r] + cvL, acc[mf][1][r] + cvR);
        }
      __syncthreads();   // LDS reads complete before next stage overwrites
    }
  }
}

// ---------------- edge scoring (compose + GEMM2 + logit), barrier-free ----------------
__global__ __launch_bounds__(256, 4) void k_score(const unsigned* __restrict__ rel_pk,
    const unsigned short* __restrict__ Wc_pk, const float* __restrict__ bc,
    const unsigned short* __restrict__ node_l, const unsigned short* __restrict__ node_r,
    const unsigned* __restrict__ qctx_p,
    const int* __restrict__ src, const int* __restrict__ dst, const int* __restrict__ eg,
    float* __restrict__ exbuf, float* __restrict__ denom){
  __shared__ char smem[16384];
  int tid = threadIdx.x;
  int l = tid & 63, wn = tid >> 6;
  char* wbase = smem + wn*4096;
  char* sLc  = wbase;            // [16][64] bf16, swz (row&12)<<3  (2KB)
  char* sRin = wbase + 2048;     // [16][64] bf16, swz (row&7)<<4   (2KB)
  int e0 = blockIdx.x * 64 + wn*16;

  // (1) index load: lanes 0-15 src, 16-31 dst, 32-47 eg
  int idxv;
  {
    int j = l & 15;
    int e = e0 + j;
    int ec = e < N_EDGES ? e : N_EDGES-1;
    const int* p = (l < 16) ? src : (l < 32) ? dst : eg;
    idxv = p[ec];
  }
  // (2) front-load: rel rows (coalesced, L3-hot) + node gathers
  unsigned rlrv[16];
  unsigned short nlv[16], nrv[16];
  #pragma unroll
  for (int j = 0; j < 16; ++j){
    int e = e0 + j;
    int ec = e < N_EDGES ? e : N_EDGES-1;
    rlrv[j] = rel_pk[(size_t)ec*64 + l];
    int s  = __shfl(idxv, j);
    int d2 = __shfl(idxv, 16 + j);
    nlv[j] = node_l[(size_t)s*64 + l];
    nrv[j] = node_r[(size_t)d2*64 + l];
  }
  // (3) compose -> sLc/sRin (wave-local)
  #pragma unroll
  for (int j = 0; j < 16; ++j){
    int e = e0 + j;
    int bL = (j << 7) + (l << 1);  bL ^= (j & 12) << 3;
    int bR = (j << 7) + (l << 1);  bR ^= (j & 7) << 4;
    unsigned short lh16 = 0, rr16 = 0;
    if (e < N_EDGES){
      int b = __shfl(idxv, 32 + j);
      unsigned qv = qctx_p[b*64 + l];
      unsigned rv = rlrv[j];
      float lh = leaky(bf2f(nlv[j]) + bf2f((unsigned short)(rv & 0xFFFFu))
                       + bf2f((unsigned short)(qv & 0xFFFFu)));
      float rr = leaky(bf2f(nrv[j]) + bf2f((unsigned short)(rv >> 16))
                       + bf2f((unsigned short)(qv >> 16)));
      lh16 = f2bf(lh); rr16 = f2bf(rr);
    }
    *(unsigned short*)(sLc + bL) = lh16;
    *(unsigned short*)(sRin + bR) = rr16;
  }
  // (4) GEMM2: RH[16][64] = sRin @ Wc (wave-local)
  float bcv[4];
  #pragma unroll
  for (int nf = 0; nf < 4; ++nf) bcv[nf] = bc[nf*16 + (l & 15)];
  f32x4 acc2[4];
  #pragma unroll
  for (int nf = 0; nf < 4; ++nf) acc2[nf] = (f32x4){0.f,0.f,0.f,0.f};
  #pragma unroll
  for (int kb = 0; kb < 2; ++kb){
    int row = l & 15;
    int byte = (row << 7) + kb*64 + ((l >> 4) << 4);
    byte ^= (row & 7) << 4;
    bf16x8 a = *(const bf16x8*)(sRin + byte);
    #pragma unroll
    for (int nf = 0; nf < 4; ++nf){
      bf16x8 bfr = *(const bf16x8*)(Wc_pk + ((size_t)(nf*2 + kb)*64 + l)*8);
      acc2[nf] = __builtin_amdgcn_mfma_f32_16x16x32_bf16(a, bfr, acc2[nf], 0, 0, 0);
    }
  }
  // (5) logit = sum_col (RH+bc)*lh, 16-lane-group reduce; tail: exp + denom atomic
  int srcj[4];
  float vr[4];
  #pragma unroll
  for (int r = 0; r < 4; ++r){
    int rowl = ((l >> 4) << 2) + r;
    srcj[r] = __shfl(idxv, rowl);
    float v = 0.f;
    #pragma unroll
    for (int nf = 0; nf < 4; ++nf){
      int col = nf*16 + (l & 15);
      int byte = (rowl << 7) + (col << 1);
      byte ^= (rowl & 12) << 3;
      v += (acc2[nf][r] + bcv[nf]) * bf2f(*(unsigned short*)(sLc + byte));
    }
    v += __shfl_xor(v, 1); v += __shfl_xor(v, 2);
    v += __shfl_xor(v, 4); v += __shfl_xor(v, 8);
    vr[r] = v;
  }
  if ((l & 15) == 0){
    #pragma unroll
    for (int r = 0; r < 4; ++r){
      int rowl = ((l >> 4) << 2) + r;
      int e = e0 + rowl;
      if (e < N_EDGES){
        float ex = __expf(vr[r]);
        exbuf[e] = ex;
        atomicAdd(&denom[srcj[r]], ex);
      }
    }
  }
}

// ---------------- final pass: trans + propagate + entity aggregate ----------------
__global__ void k_passC(const float* __restrict__ exbuf, const float* __restrict__ denom,
                        const int* __restrict__ src, const int* __restrict__ dst,
                        const float* __restrict__ node_score, const int* __restrict__ ent,
                        float* __restrict__ out){
  int e = blockIdx.x*256 + threadIdx.x;
  if (e >= N_EDGES) return;
  int s = src[e];
  float tr = exbuf[e] / denom[s];
  atomicAdd(&out[ent[dst[e]]], tr * node_score[s]);
}

// ---------------- host ----------------
extern "C" void kernel_launch(void* const* d_in, const int* in_sizes, int n_in,
                              void* d_out, int out_size, void* d_ws, size_t ws_size,
                              hipStream_t stream){
  const float* mem   = (const float*)d_in[0];
  const float* nsc   = (const float*)d_in[1];
  const float* relE  = (const float*)d_in[2];
  const float* qsrc  = (const float*)d_in[3];
  const float* qrel  = (const float*)d_in[4];
  const int*   eg    = (const int*)d_in[5];
  const int*   src   = (const int*)d_in[6];
  const int*   dst   = (const int*)d_in[7];
  const int*   ent   = (const int*)d_in[8];
  const float* Wp    = (const float*)d_in[9];
  const float* bp    = (const float*)d_in[10];
  const float* Ws    = (const float*)d_in[11];
  const float* bs    = (const float*)d_in[12];
  const float* Wbs   = (const float*)d_in[13];
  const float* bbs   = (const float*)d_in[14];
  const float* Wl    = (const float*)d_in[15];
  const float* bl    = (const float*)d_in[16];
  const float* Wr    = (const float*)d_in[17];
  const float* br    = (const float*)d_in[18];
  const float* Wc    = (const float*)d_in[19];
  const float* bc    = (const float*)d_in[20];
  float* out = (float*)d_out;

  char* w = (char*)d_ws;
  auto alloc = [&](size_t bytes)->void*{
    void* p = (void*)w; w += (bytes + 255) & ~(size_t)255; return p;
  };
  float* Wnlr = (float*)alloc(32768*4);
  float* Wrlr = (float*)alloc(32768*4);
  unsigned short* Wbs_pk = (unsigned short*)alloc(65536*2);
  unsigned short* Wn_pk  = (unsigned short*)alloc(32768*2);
  unsigned short* Wr_pk  = (unsigned short*)alloc(32768*2);
  unsigned short* Wc_pk  = (unsigned short*)alloc(4096*2);
  float* cv  = (float*)alloc(256*4);
  float* qs  = (float*)alloc((size_t)N_Q*SSM*4);
  float* qr  = (float*)alloc((size_t)N_Q*DSM*4);
  unsigned* qctx_p = (unsigned*)alloc((size_t)N_Q*DSM*4);
  unsigned short* node_l = (unsigned short*)alloc((size_t)N_NODES*64*2);
  unsigned short* node_r = (unsigned short*)alloc((size_t)N_NODES*64*2);
  unsigned* rel_pk = (unsigned*)alloc((size_t)N_EDGES*64*4);
  float* exbuf  = (float*)alloc((size_t)N_EDGES*4);
  float* denom = (float*)alloc((size_t)N_NODES*4);

  k_setup1<<<1121, 256, 0, stream>>>(out, denom,
                                     Wp, Wl, Wr, Wnlr, Wrlr, bp, cv,
                                     qsrc, Ws, bs, qrel, qs, qr,
                                     Wbs, Wbs_pk, Wc, Wc_pk);
  k_setup2<<<64, 256, 0, stream>>>(qs, qr, Wl, bl, Wr, br, qctx_p,
                                   Wnlr, Wn_pk, Wrlr, Wr_pk);
  k_proj<<<GRID_GROUPS*5, 256, 0, stream>>>(mem, Wbs_pk, bbs, Wn_pk, cv, node_l, node_r,
                                            relE, Wr_pk, rel_pk);
  k_score<<<(N_EDGES+63)/64, 256, 0, stream>>>(rel_pk, Wc_pk, bc, node_l, node_r, qctx_p,
                                               src, dst, eg, exbuf, denom);
  k_passC<<<(N_EDGES+255)/256, 256, 0, stream>>>(exbuf, denom, src, dst, nsc, ent, out);
}

// Round 15
// 244.659 us; speedup vs baseline: 1.4656x; 1.4656x over previous
//
#include <hip/hip_runtime.h>
#include <hip/hip_bf16.h>

#define N_NODES 200000
#define N_EDGES 300000
#define N_Q     128
#define N_ENT   50000
#define D       256
#define DSM     64
#define SDIM    128
#define SSM     32

#define NODE_TILES 6250
#define REL_TILES  9375
#define GROUPS    3125

typedef __attribute__((ext_vector_type(8))) short bf16x8;
typedef __attribute__((ext_vector_type(4))) float f32x4;

__device__ __forceinline__ float leaky(float x){ return x > 0.f ? x : 0.01f*x; }

__device__ __forceinline__ unsigned short f2bf(float f){
  __hip_bfloat16 h = __float2bfloat16(f);
  return *reinterpret_cast<unsigned short*>(&h);
}
__device__ __forceinline__ unsigned pk2bf(float a, float b){
  float2 t; t.x = a; t.y = b;
  __hip_bfloat162 h = __float22bfloat162_rn(t);
  return *reinterpret_cast<unsigned*>(&h);
}
__device__ __forceinline__ float bf2f(unsigned short h){
  return __uint_as_float(((unsigned)h) << 16);
}

// async global->LDS, 16B per lane; gptr per-lane, lptr wave-uniform base (lane*16 auto)
__device__ __forceinline__ void gll16(const void* g, void* l){
  __builtin_amdgcn_global_load_lds(
      (const __attribute__((address_space(1))) void*)g,
      (__attribute__((address_space(3))) void*)l, 16, 0, 0);
}

// convert 8 fp32 (two float4) -> bf16x8 fragment
__device__ __forceinline__ bf16x8 cvt8(float4 a, float4 b){
  union { bf16x8 v; unsigned u[4]; } r;
  r.u[0] = pk2bf(a.x, a.y); r.u[1] = pk2bf(a.z, a.w);
  r.u[2] = pk2bf(b.x, b.y); r.u[3] = pk2bf(b.z, b.w);
  return r.v;
}

// pack fp32 [K][N] row-major -> bf16 MFMA B-fragment order.
__device__ __forceinline__ void dev_pack(const float* __restrict__ src,
                                         unsigned short* __restrict__ dst,
                                         int K, int N, int id, int total){
  if (id >= total) return;
  int lane = id & 63, fb = id >> 6;
  int KB = K >> 5;
  int kb = fb % KB, nb = fb / KB;
  int k0 = kb*32 + ((lane>>4)<<3);
  int n  = nb*16 + (lane & 15);
  #pragma unroll
  for (int i = 0; i < 8; ++i) dst[(size_t)id*8 + i] = f2bf(src[(size_t)(k0+i)*N + n]);
}

// ---------------- fused setup stage 1 ----------------
__global__ void k_setup1(float* out, float* denom,
                         const float* __restrict__ Wp, const float* __restrict__ Wl,
                         const float* __restrict__ Wr, float* Wnlr, float* Wrlr,
                         const float* __restrict__ bp, float* cv,
                         const float* __restrict__ qsrc, const float* __restrict__ Ws,
                         const float* __restrict__ bs, const float* __restrict__ qrel,
                         float* qs, float* qr,
                         const float* __restrict__ Wbs, unsigned short* Wbs_pk,
                         const float* __restrict__ Wc, unsigned short* Wc_pk){
  int b = blockIdx.x, tid = threadIdx.x;
  if (b < 782){
    int id = b*256 + tid;
    if (id < N_ENT) out[id] = 0.f;
    if (id < N_NODES) denom[id] = 0.f;
  } else if (b < 1038){
    int id = (b-782)*256 + tid;
    int m = id >> 14, rem = id & 16383, k = rem >> 6, c = rem & 63;
    const float* Wsrc = (m & 1) ? Wr : Wl;
    int roff = (m >> 1) * 64;
    float s = 0.f;
    for (int i = 0; i < 64; ++i) s += Wp[k*64+i] * Wsrc[(roff+i)*64 + c];
    float* o = (m >> 1) ? Wrlr : Wnlr;
    o[k*128 + (m&1)*64 + c] = s;
  } else if (b == 1038){
    int m = tid >> 6, c = tid & 63;
    const float* Wsrc = (m & 1) ? Wr : Wl;
    int roff = (m >> 1) * 64;
    float s = 0.f;
    for (int i = 0; i < 64; ++i) s += bp[i] * Wsrc[(roff+i)*64 + c];
    cv[tid] = s;
  } else if (b < 1087){
    int id = (b-1039)*256 + tid;
    if (id < N_Q*SSM){
      int q = id >> 5, i = id & 31;
      float s = bs[i];
      for (int j = 0; j < SDIM; ++j) s += qsrc[q*SDIM+j] * Ws[j*SSM+i];
      qs[id] = s;
    } else {
      int id2 = id - N_Q*SSM;
      int q = id2 >> 6, i = id2 & 63;
      float s = bp[i];
      for (int j = 0; j < D; ++j) s += qrel[q*D+j] * Wp[j*DSM+i];
      qr[id2] = s;
    }
  } else if (b < 1119){
    dev_pack(Wbs, Wbs_pk, 256, 256, (b-1087)*256 + tid, 8192);
  } else {
    dev_pack(Wc, Wc_pk, 64, 64, (b-1119)*256 + tid, 512);
  }
}

// ---------------- fused setup stage 2 ----------------
__global__ void k_setup2(const float* __restrict__ qs, const float* __restrict__ qr,
                         const float* __restrict__ Wl, const float* __restrict__ bl,
                         const float* __restrict__ Wr, const float* __restrict__ br,
                         unsigned* qctx_p,
                         const float* __restrict__ Wnlr, unsigned short* Wn_pk,
                         const float* __restrict__ Wrlr, unsigned short* Wr_pk){
  int b = blockIdx.x, tid = threadIdx.x;
  if (b < 32){
    int id = b*256 + tid;                 // 8192 = 128q * 64c
    int q = id >> 6, c = id & 63;
    float sl = bl[c], sr = br[c];
    for (int i = 0; i < SSM; ++i){
      float v = qs[q*SSM+i];
      sl += v * Wl[(128+i)*64+c];
      sr += v * Wr[(128+i)*64+c];
    }
    for (int i = 0; i < DSM; ++i){
      float v = qr[q*DSM+i];
      sl += v * Wl[(160+i)*64+c];
      sr += v * Wr[(160+i)*64+c];
    }
    qctx_p[id] = pk2bf(sl, sr);
  } else if (b < 48){
    dev_pack(Wnlr, Wn_pk, 256, 128, (b-32)*256 + tid, 4096);
  } else {
    dev_pack(Wrlr, Wr_pk, 256, 128, (b-48)*256 + tid, 4096);
  }
}

// ---------------- fused projection kernel: gll-staged fp32 tiles ----------------
// 32-row fp32 tile (32KB LDS) staged via global_load_lds (no VGPR round-trip,
// no staging VALU). LDS dest is LINEAR (gll constraint); global source is
// pre-swizzled lane*16 ^ ((row&7)<<4); GEMM1 A-reads apply the same XOR
// (rule 21: inverse-swz source + swz read). cvt fp32->bf16 in the MFMA loop.
__global__ __launch_bounds__(256) void k_proj(const float* __restrict__ A,
    const unsigned short* __restrict__ Wbs_pk, const float* __restrict__ bbs,
    const unsigned short* __restrict__ Wn_pk, const float* __restrict__ cv,
    unsigned short* __restrict__ node_l, unsigned short* __restrict__ node_r,
    const float* __restrict__ relE, const unsigned short* __restrict__ Wr_pk,
    unsigned* __restrict__ rel_pk){
  __shared__ char smem[32768];            // fp32 [32][256] tile
  int tid = threadIdx.x;
  int l = tid & 63, wn = tid >> 6;
  int g = blockIdx.x / 5, r5 = blockIdx.x % 5;

  // A-fragment read: logical row, kb -> two float4 from swizzled fp32 LDS
  auto readA = [&](int row, int kb)->bf16x8{
    int swz = (row & 7) << 4;
    int c0 = kb*128 + ((l >> 4) << 5);            // 32B-aligned logical col byte
    float4 f0 = *(const float4*)(smem + row*1024 + (c0 ^ swz));
    float4 f1 = *(const float4*)(smem + row*1024 + ((c0 + 16) ^ swz));
    return cvt8(f0, f1);
  };

  if (r5 < 2){
    // ================= node path =================
    int row0 = (g*2 + r5) * 32;
    // stage: wave wn issues rows {i*4+wn}, per-lane source pre-swizzled
    #pragma unroll
    for (int i = 0; i < 8; ++i){
      int row = i*4 + wn;
      const char* src = (const char*)(A + (size_t)(row0 + row)*256)
                        + ((l*16) ^ ((row & 7) << 4));
      gll16(src, smem + row*1024);
    }
    __syncthreads();                               // vmcnt(0) drain = staging wait
    f32x4 acc[2][4];
    #pragma unroll
    for (int mf = 0; mf < 2; ++mf)
      #pragma unroll
      for (int nf = 0; nf < 4; ++nf) acc[mf][nf] = (f32x4){0.f,0.f,0.f,0.f};
    for (int kb = 0; kb < 8; ++kb){
      bf16x8 a[2], b[4];
      #pragma unroll
      for (int mf = 0; mf < 2; ++mf) a[mf] = readA(mf*16 + (l & 15), kb);
      #pragma unroll
      for (int nf = 0; nf < 4; ++nf){
        int nbb = wn*4 + nf;
        b[nf] = *(const bf16x8*)(Wbs_pk + ((size_t)(nbb*8 + kb)*64 + l)*8);
      }
      #pragma unroll
      for (int mf = 0; mf < 2; ++mf)
        #pragma unroll
        for (int nf = 0; nf < 4; ++nf)
          acc[mf][nf] = __builtin_amdgcn_mfma_f32_16x16x32_bf16(a[mf], b[nf], acc[mf][nf], 0, 0, 0);
    }
    __syncthreads();
    // epilogue 1: emb2 bf16 -> first 16KB of smem, swz (row&7)<<4 (R12 scheme)
    #pragma unroll
    for (int mf = 0; mf < 2; ++mf)
      #pragma unroll
      for (int nf = 0; nf < 4; ++nf){
        int col = wn*64 + nf*16 + (l & 15);
        float bb = bbs[col];
        #pragma unroll
        for (int r = 0; r < 4; ++r){
          int row = mf*16 + ((l >> 4) << 2) + r;
          int byte = (row << 9) + col*2;
          byte ^= (row & 7) << 4;
          *(unsigned short*)(smem + byte) = f2bf(leaky(acc[mf][nf][r] + bb));
        }
      }
    __syncthreads();
    f32x4 acc2[2][2];
    #pragma unroll
    for (int mf = 0; mf < 2; ++mf){ acc2[mf][0] = (f32x4){0.f,0.f,0.f,0.f}; acc2[mf][1] = (f32x4){0.f,0.f,0.f,0.f}; }
    for (int kb = 0; kb < 8; ++kb){
      bf16x8 a[2], b[2];
      #pragma unroll
      for (int mf = 0; mf < 2; ++mf){
        int row = mf*16 + (l & 15);
        int byte = (row << 9) + kb*64 + ((l >> 4) << 4);
        byte ^= (row & 7) << 4;
        a[mf] = *(const bf16x8*)(smem + byte);
      }
      #pragma unroll
      for (int nf = 0; nf < 2; ++nf){
        int nbb = wn*2 + nf;
        b[nf] = *(const bf16x8*)(Wn_pk + ((size_t)(nbb*8 + kb)*64 + l)*8);
      }
      #pragma unroll
      for (int mf = 0; mf < 2; ++mf)
        #pragma unroll
        for (int nf = 0; nf < 2; ++nf)
          acc2[mf][nf] = __builtin_amdgcn_mfma_f32_16x16x32_bf16(a[mf], b[nf], acc2[mf][nf], 0, 0, 0);
    }
    #pragma unroll
    for (int mf = 0; mf < 2; ++mf)
      #pragma unroll
      for (int nf = 0; nf < 2; ++nf){
        int col = wn*32 + nf*16 + (l & 15);
        float cc = cv[col];
        #pragma unroll
        for (int r = 0; r < 4; ++r){
          int row = mf*16 + ((l >> 4) << 2) + r;
          unsigned short h = f2bf(acc2[mf][nf][r] + cc);
          size_t gg = (size_t)(row0 + row);
          if (col < 64) node_l[gg*64 + col] = h;
          else          node_r[gg*64 + col - 64] = h;
        }
      }
  } else {
    // ================= rel path =================
    int row0 = (g*3 + (r5 - 2)) * 32;
    #pragma unroll
    for (int i = 0; i < 8; ++i){
      int row = i*4 + wn;
      const char* src = (const char*)(relE + (size_t)(row0 + row)*256)
                        + ((l*16) ^ ((row & 7) << 4));
      gll16(src, smem + row*1024);
    }
    __syncthreads();
    f32x4 acc[2][2];
    #pragma unroll
    for (int mf = 0; mf < 2; ++mf){ acc[mf][0] = (f32x4){0.f,0.f,0.f,0.f}; acc[mf][1] = (f32x4){0.f,0.f,0.f,0.f}; }
    for (int kb = 0; kb < 8; ++kb){
      bf16x8 a[2], b0, b1;
      #pragma unroll
      for (int mf = 0; mf < 2; ++mf) a[mf] = readA(mf*16 + (l & 15), kb);
      b0 = *(const bf16x8*)(Wr_pk + ((size_t)(wn*8 + kb)*64 + l)*8);        // left  nb=wn
      b1 = *(const bf16x8*)(Wr_pk + ((size_t)((4+wn)*8 + kb)*64 + l)*8);    // right nb=4+wn
      #pragma unroll
      for (int mf = 0; mf < 2; ++mf){
        acc[mf][0] = __builtin_amdgcn_mfma_f32_16x16x32_bf16(a[mf], b0, acc[mf][0], 0, 0, 0);
        acc[mf][1] = __builtin_amdgcn_mfma_f32_16x16x32_bf16(a[mf], b1, acc[mf][1], 0, 0, 0);
      }
    }
    int c = wn*16 + (l & 15);
    float cvL = cv[128 + c], cvR = cv[192 + c];
    #pragma unroll
    for (int mf = 0; mf < 2; ++mf)
      #pragma unroll
      for (int r = 0; r < 4; ++r){
        int row = mf*16 + ((l >> 4) << 2) + r;
        rel_pk[(size_t)(row0 + row)*64 + c] = pk2bf(acc[mf][0][r] + cvL, acc[mf][1][r] + cvR);
      }
  }
}

// ---------------- edge scoring (compose + GEMM2 + logit), barrier-free ----------------
__global__ __launch_bounds__(256, 4) void k_score(const unsigned* __restrict__ rel_pk,
    const unsigned short* __restrict__ Wc_pk, const float* __restrict__ bc,
    const unsigned short* __restrict__ node_l, const unsigned short* __restrict__ node_r,
    const unsigned* __restrict__ qctx_p,
    const int* __restrict__ src, const int* __restrict__ dst, const int* __restrict__ eg,
    float* __restrict__ exbuf, float* __restrict__ denom){
  __shared__ char smem[16384];
  int tid = threadIdx.x;
  int l = tid & 63, wn = tid >> 6;
  char* wbase = smem + wn*4096;
  char* sLc  = wbase;            // [16][64] bf16, swz (row&12)<<3  (2KB)
  char* sRin = wbase + 2048;     // [16][64] bf16, swz (row&7)<<4   (2KB)
  int e0 = blockIdx.x * 64 + wn*16;

  // (1) index load: lanes 0-15 src, 16-31 dst, 32-47 eg
  int idxv;
  {
    int j = l & 15;
    int e = e0 + j;
    int ec = e < N_EDGES ? e : N_EDGES-1;
    const int* p = (l < 16) ? src : (l < 32) ? dst : eg;
    idxv = p[ec];
  }
  // (2) front-load: rel rows (coalesced, L3-hot) + node gathers
  unsigned rlrv[16];
  unsigned short nlv[16], nrv[16];
  #pragma unroll
  for (int j = 0; j < 16; ++j){
    int e = e0 + j;
    int ec = e < N_EDGES ? e : N_EDGES-1;
    rlrv[j] = rel_pk[(size_t)ec*64 + l];
    int s  = __shfl(idxv, j);
    int d2 = __shfl(idxv, 16 + j);
    nlv[j] = node_l[(size_t)s*64 + l];
    nrv[j] = node_r[(size_t)d2*64 + l];
  }
  // (3) compose -> sLc/sRin (wave-local)
  #pragma unroll
  for (int j = 0; j < 16; ++j){
    int e = e0 + j;
    int bL = (j << 7) + (l << 1);  bL ^= (j & 12) << 3;
    int bR = (j << 7) + (l << 1);  bR ^= (j & 7) << 4;
    unsigned short lh16 = 0, rr16 = 0;
    if (e < N_EDGES){
      int b = __shfl(idxv, 32 + j);
      unsigned qv = qctx_p[b*64 + l];
      unsigned rv = rlrv[j];
      float lh = leaky(bf2f(nlv[j]) + bf2f((unsigned short)(rv & 0xFFFFu))
                       + bf2f((unsigned short)(qv & 0xFFFFu)));
      float rr = leaky(bf2f(nrv[j]) + bf2f((unsigned short)(rv >> 16))
                       + bf2f((unsigned short)(qv >> 16)));
      lh16 = f2bf(lh); rr16 = f2bf(rr);
    }
    *(unsigned short*)(sLc + bL) = lh16;
    *(unsigned short*)(sRin + bR) = rr16;
  }
  // (4) GEMM2: RH[16][64] = sRin @ Wc (wave-local)
  float bcv[4];
  #pragma unroll
  for (int nf = 0; nf < 4; ++nf) bcv[nf] = bc[nf*16 + (l & 15)];
  f32x4 acc2[4];
  #pragma unroll
  for (int nf = 0; nf < 4; ++nf) acc2[nf] = (f32x4){0.f,0.f,0.f,0.f};
  #pragma unroll
  for (int kb = 0; kb < 2; ++kb){
    int row = l & 15;
    int byte = (row << 7) + kb*64 + ((l >> 4) << 4);
    byte ^= (row & 7) << 4;
    bf16x8 a = *(const bf16x8*)(sRin + byte);
    #pragma unroll
    for (int nf = 0; nf < 4; ++nf){
      bf16x8 bfr = *(const bf16x8*)(Wc_pk + ((size_t)(nf*2 + kb)*64 + l)*8);
      acc2[nf] = __builtin_amdgcn_mfma_f32_16x16x32_bf16(a, bfr, acc2[nf], 0, 0, 0);
    }
  }
  // (5) logit = sum_col (RH+bc)*lh, 16-lane-group reduce; tail: exp + denom atomic
  int srcj[4];
  float vr[4];
  #pragma unroll
  for (int r = 0; r < 4; ++r){
    int rowl = ((l >> 4) << 2) + r;
    srcj[r] = __shfl(idxv, rowl);
    float v = 0.f;
    #pragma unroll
    for (int nf = 0; nf < 4; ++nf){
      int col = nf*16 + (l & 15);
      int byte = (rowl << 7) + (col << 1);
      byte ^= (rowl & 12) << 3;
      v += (acc2[nf][r] + bcv[nf]) * bf2f(*(unsigned short*)(sLc + byte));
    }
    v += __shfl_xor(v, 1); v += __shfl_xor(v, 2);
    v += __shfl_xor(v, 4); v += __shfl_xor(v, 8);
    vr[r] = v;
  }
  if ((l & 15) == 0){
    #pragma unroll
    for (int r = 0; r < 4; ++r){
      int rowl = ((l >> 4) << 2) + r;
      int e = e0 + rowl;
      if (e < N_EDGES){
        float ex = __expf(vr[r]);
        exbuf[e] = ex;
        atomicAdd(&denom[srcj[r]], ex);
      }
    }
  }
}

// ---------------- final pass: trans + propagate + entity aggregate ----------------
__global__ void k_passC(const float* __restrict__ exbuf, const float* __restrict__ denom,
                        const int* __restrict__ src, const int* __restrict__ dst,
                        const float* __restrict__ node_score, const int* __restrict__ ent,
                        float* __restrict__ out){
  int e = blockIdx.x*256 + threadIdx.x;
  if (e >= N_EDGES) return;
  int s = src[e];
  float tr = exbuf[e] / denom[s];
  atomicAdd(&out[ent[dst[e]]], tr * node_score[s]);
}

// ---------------- host ----------------
extern "C" void kernel_launch(void* const* d_in, const int* in_sizes, int n_in,
                              void* d_out, int out_size, void* d_ws, size_t ws_size,
                              hipStream_t stream){
  const float* mem   = (const float*)d_in[0];
  const float* nsc   = (const float*)d_in[1];
  const float* relE  = (const float*)d_in[2];
  const float* qsrc  = (const float*)d_in[3];
  const float* qrel  = (const float*)d_in[4];
  const int*   eg    = (const int*)d_in[5];
  const int*   src   = (const int*)d_in[6];
  const int*   dst   = (const int*)d_in[7];
  const int*   ent   = (const int*)d_in[8];
  const float* Wp    = (const float*)d_in[9];
  const float* bp    = (const float*)d_in[10];
  const float* Ws    = (const float*)d_in[11];
  const float* bs    = (const float*)d_in[12];
  const float* Wbs   = (const float*)d_in[13];
  const float* bbs   = (const float*)d_in[14];
  const float* Wl    = (const float*)d_in[15];
  const float* bl    = (const float*)d_in[16];
  const float* Wr    = (const float*)d_in[17];
  const float* br    = (const float*)d_in[18];
  const float* Wc    = (const float*)d_in[19];
  const float* bc    = (const float*)d_in[20];
  float* out = (float*)d_out;

  char* w = (char*)d_ws;
  auto alloc = [&](size_t bytes)->void*{
    void* p = (void*)w; w += (bytes + 255) & ~(size_t)255; return p;
  };
  float* Wnlr = (float*)alloc(32768*4);
  float* Wrlr = (float*)alloc(32768*4);
  unsigned short* Wbs_pk = (unsigned short*)alloc(65536*2);
  unsigned short* Wn_pk  = (unsigned short*)alloc(32768*2);
  unsigned short* Wr_pk  = (unsigned short*)alloc(32768*2);
  unsigned short* Wc_pk  = (unsigned short*)alloc(4096*2);
  float* cv  = (float*)alloc(256*4);
  float* qs  = (float*)alloc((size_t)N_Q*SSM*4);
  float* qr  = (float*)alloc((size_t)N_Q*DSM*4);
  unsigned* qctx_p = (unsigned*)alloc((size_t)N_Q*DSM*4);
  unsigned short* node_l = (unsigned short*)alloc((size_t)N_NODES*64*2);
  unsigned short* node_r = (unsigned short*)alloc((size_t)N_NODES*64*2);
  unsigned* rel_pk = (unsigned*)alloc((size_t)N_EDGES*64*4);
  float* exbuf  = (float*)alloc((size_t)N_EDGES*4);
  float* denom = (float*)alloc((size_t)N_NODES*4);

  k_setup1<<<1121, 256, 0, stream>>>(out, denom,
                                     Wp, Wl, Wr, Wnlr, Wrlr, bp, cv,
                                     qsrc, Ws, bs, qrel, qs, qr,
                                     Wbs, Wbs_pk, Wc, Wc_pk);
  k_setup2<<<64, 256, 0, stream>>>(qs, qr, Wl, bl, Wr, br, qctx_p,
                                   Wnlr, Wn_pk, Wrlr, Wr_pk);
  k_proj<<<GROUPS*5, 256, 0, stream>>>(mem, Wbs_pk, bbs, Wn_pk, cv, node_l, node_r,
                                       relE, Wr_pk, rel_pk);
  k_score<<<(N_EDGES+63)/64, 256, 0, stream>>>(rel_pk, Wc_pk, bc, node_l, node_r, qctx_p,
                                               src, dst, eg, exbuf, denom);
  k_passC<<<(N_EDGES+255)/256, 256, 0, stream>>>(exbuf, denom, src, dst, nsc, ent, out);
}

// Round 16
// 231.243 us; speedup vs baseline: 1.5506x; 1.0580x over previous
//
#include <hip/hip_runtime.h>
#include <hip/hip_bf16.h>

#define N_NODES 200000
#define N_EDGES 300000
#define N_Q     128
#define N_ENT   50000
#define D       256
#define DSM     64
#define SDIM    128
#define SSM     32

#define NODE_BLKS 3125
#define REL_BLKS  4688

typedef __attribute__((ext_vector_type(8))) short bf16x8;
typedef __attribute__((ext_vector_type(4))) float f32x4;

__device__ __forceinline__ float leaky(float x){ return x > 0.f ? x : 0.01f*x; }

__device__ __forceinline__ unsigned short f2bf(float f){
  __hip_bfloat16 h = __float2bfloat16(f);
  return *reinterpret_cast<unsigned short*>(&h);
}
__device__ __forceinline__ unsigned pk2bf(float a, float b){
  float2 t; t.x = a; t.y = b;
  __hip_bfloat162 h = __float22bfloat162_rn(t);
  return *reinterpret_cast<unsigned*>(&h);
}
__device__ __forceinline__ float bf2f(unsigned short h){
  return __uint_as_float(((unsigned)h) << 16);
}

// pack fp32 [K][N] row-major -> bf16 MFMA B-fragment order.
__device__ __forceinline__ void dev_pack(const float* __restrict__ src,
                                         unsigned short* __restrict__ dst,
                                         int K, int N, int id, int total){
  if (id >= total) return;
  int lane = id & 63, fb = id >> 6;
  int KB = K >> 5;
  int kb = fb % KB, nb = fb / KB;
  int k0 = kb*32 + ((lane>>4)<<3);
  int n  = nb*16 + (lane & 15);
  #pragma unroll
  for (int i = 0; i < 8; ++i) dst[(size_t)id*8 + i] = f2bf(src[(size_t)(k0+i)*N + n]);
}

// ---------------- fused setup stage 1 ----------------
__global__ void k_setup1(float* out, float* denom,
                         const float* __restrict__ Wp, const float* __restrict__ Wl,
                         const float* __restrict__ Wr, float* Wnlr, float* Wrlr,
                         const float* __restrict__ bp, float* cv,
                         const float* __restrict__ qsrc, const float* __restrict__ Ws,
                         const float* __restrict__ bs, const float* __restrict__ qrel,
                         float* qs, float* qr,
                         const float* __restrict__ Wbs, unsigned short* Wbs_pk,
                         const float* __restrict__ Wc, unsigned short* Wc_pk){
  int b = blockIdx.x, tid = threadIdx.x;
  if (b < 782){
    int id = b*256 + tid;
    if (id < N_ENT) out[id] = 0.f;
    if (id < N_NODES) denom[id] = 0.f;
  } else if (b < 1038){
    int id = (b-782)*256 + tid;
    int m = id >> 14, rem = id & 16383, k = rem >> 6, c = rem & 63;
    const float* Wsrc = (m & 1) ? Wr : Wl;
    int roff = (m >> 1) * 64;
    float s = 0.f;
    for (int i = 0; i < 64; ++i) s += Wp[k*64+i] * Wsrc[(roff+i)*64 + c];
    float* o = (m >> 1) ? Wrlr : Wnlr;
    o[k*128 + (m&1)*64 + c] = s;
  } else if (b == 1038){
    int m = tid >> 6, c = tid & 63;
    const float* Wsrc = (m & 1) ? Wr : Wl;
    int roff = (m >> 1) * 64;
    float s = 0.f;
    for (int i = 0; i < 64; ++i) s += bp[i] * Wsrc[(roff+i)*64 + c];
    cv[tid] = s;
  } else if (b < 1087){
    int id = (b-1039)*256 + tid;
    if (id < N_Q*SSM){
      int q = id >> 5, i = id & 31;
      float s = bs[i];
      for (int j = 0; j < SDIM; ++j) s += qsrc[q*SDIM+j] * Ws[j*SSM+i];
      qs[id] = s;
    } else {
      int id2 = id - N_Q*SSM;
      int q = id2 >> 6, i = id2 & 63;
      float s = bp[i];
      for (int j = 0; j < D; ++j) s += qrel[q*D+j] * Wp[j*DSM+i];
      qr[id2] = s;
    }
  } else if (b < 1119){
    dev_pack(Wbs, Wbs_pk, 256, 256, (b-1087)*256 + tid, 8192);
  } else {
    dev_pack(Wc, Wc_pk, 64, 64, (b-1119)*256 + tid, 512);
  }
}

// ---------------- fused setup stage 2 ----------------
__global__ void k_setup2(const float* __restrict__ qs, const float* __restrict__ qr,
                         const float* __restrict__ Wl, const float* __restrict__ bl,
                         const float* __restrict__ Wr, const float* __restrict__ br,
                         unsigned* qctx_p,
                         const float* __restrict__ Wnlr, unsigned short* Wn_pk,
                         const float* __restrict__ Wrlr, unsigned short* Wr_pk){
  int b = blockIdx.x, tid = threadIdx.x;
  if (b < 32){
    int id = b*256 + tid;                 // 8192 = 128q * 64c
    int q = id >> 6, c = id & 63;
    float sl = bl[c], sr = br[c];
    for (int i = 0; i < SSM; ++i){
      float v = qs[q*SSM+i];
      sl += v * Wl[(128+i)*64+c];
      sr += v * Wr[(128+i)*64+c];
    }
    for (int i = 0; i < DSM; ++i){
      float v = qr[q*DSM+i];
      sl += v * Wl[(160+i)*64+c];
      sr += v * Wr[(160+i)*64+c];
    }
    qctx_p[id] = pk2bf(sl, sr);
  } else if (b < 48){
    dev_pack(Wnlr, Wn_pk, 256, 128, (b-32)*256 + tid, 4096);
  } else {
    dev_pack(Wrlr, Wr_pk, 256, 128, (b-48)*256 + tid, 4096);
  }
}

// ---------------- fused projection kernel: node GEMM + rel GEMM interleaved ----------------
// Groups of 5 blocks: 2 node-blocks + 3 rel-blocks (ratio 3125:4688), so both
// phases are co-resident machine-wide: node's MFMA/barrier stalls absorb rel's
// HBM waits and vice versa (m114: co-scheduled time ~= max, not sum).
__global__ __launch_bounds__(256) void k_proj(const float* __restrict__ A,
    const unsigned short* __restrict__ Wbs_pk, const float* __restrict__ bbs,
    const unsigned short* __restrict__ Wn_pk, const float* __restrict__ cv,
    unsigned short* __restrict__ node_l, unsigned short* __restrict__ node_r,
    const float* __restrict__ relE, const unsigned short* __restrict__ Wr_pk,
    unsigned* __restrict__ rel_pk){
  __shared__ char smem[32768];
  int tid = threadIdx.x;
  int l = tid & 63, wn = tid >> 6;
  int g = blockIdx.x / 5, r5 = blockIdx.x % 5;

  if (r5 < 2){
    // ---------- node path ----------
    int nb = g*2 + r5;
    if (nb >= NODE_BLKS) return;
    int row0 = nb * 64;
    {
      const float4* Ag = (const float4*)(A + (size_t)row0 * 256);
      #pragma unroll
      for (int it = 0; it < 16; ++it){
        int f = tid + 256*it;
        int r = f >> 6, c4 = f & 63;
        float4 v = Ag[f];
        uint2 u;
        u.x = pk2bf(v.x, v.y);
        u.y = pk2bf(v.z, v.w);
        int byte = (r << 9) + (c4 << 3);
        byte ^= (r & 7) << 4;
        *(uint2*)(smem + byte) = u;
      }
    }
    __syncthreads();
    f32x4 acc[4][4];
    #pragma unroll
    for (int mf = 0; mf < 4; ++mf)
      #pragma unroll
      for (int nf = 0; nf < 4; ++nf) acc[mf][nf] = (f32x4){0.f,0.f,0.f,0.f};
    for (int kb = 0; kb < 8; ++kb){
      bf16x8 a[4], b[4];
      #pragma unroll
      for (int mf = 0; mf < 4; ++mf){
        int row = mf*16 + (l & 15);
        int byte = (row << 9) + kb*64 + ((l >> 4) << 4);
        byte ^= (row & 7) << 4;
        a[mf] = *(const bf16x8*)(smem + byte);
      }
      #pragma unroll
      for (int nf = 0; nf < 4; ++nf){
        int nbb = wn*4 + nf;
        b[nf] = *(const bf16x8*)(Wbs_pk + ((size_t)(nbb*8 + kb)*64 + l)*8);
      }
      #pragma unroll
      for (int mf = 0; mf < 4; ++mf)
        #pragma unroll
        for (int nf = 0; nf < 4; ++nf)
          acc[mf][nf] = __builtin_amdgcn_mfma_f32_16x16x32_bf16(a[mf], b[nf], acc[mf][nf], 0, 0, 0);
    }
    __syncthreads();
    #pragma unroll
    for (int mf = 0; mf < 4; ++mf)
      #pragma unroll
      for (int nf = 0; nf < 4; ++nf){
        int col = wn*64 + nf*16 + (l & 15);
        float bb = bbs[col];
        #pragma unroll
        for (int r = 0; r < 4; ++r){
          int row = mf*16 + ((l >> 4) << 2) + r;
          int byte = (row << 9) + col*2;
          byte ^= (row & 7) << 4;
          *(unsigned short*)(smem + byte) = f2bf(leaky(acc[mf][nf][r] + bb));
        }
      }
    __syncthreads();
    f32x4 acc2[4][2];
    #pragma unroll
    for (int mf = 0; mf < 4; ++mf){ acc2[mf][0] = (f32x4){0.f,0.f,0.f,0.f}; acc2[mf][1] = (f32x4){0.f,0.f,0.f,0.f}; }
    for (int kb = 0; kb < 8; ++kb){
      bf16x8 a[4], b[2];
      #pragma unroll
      for (int mf = 0; mf < 4; ++mf){
        int row = mf*16 + (l & 15);
        int byte = (row << 9) + kb*64 + ((l >> 4) << 4);
        byte ^= (row & 7) << 4;
        a[mf] = *(const bf16x8*)(smem + byte);
      }
      #pragma unroll
      for (int nf = 0; nf < 2; ++nf){
        int nbb = wn*2 + nf;
        b[nf] = *(const bf16x8*)(Wn_pk + ((size_t)(nbb*8 + kb)*64 + l)*8);
      }
      #pragma unroll
      for (int mf = 0; mf < 4; ++mf)
        #pragma unroll
        for (int nf = 0; nf < 2; ++nf)
          acc2[mf][nf] = __builtin_amdgcn_mfma_f32_16x16x32_bf16(a[mf], b[nf], acc2[mf][nf], 0, 0, 0);
    }
    #pragma unroll
    for (int mf = 0; mf < 4; ++mf)
      #pragma unroll
      for (int nf = 0; nf < 2; ++nf){
        int col = wn*32 + nf*16 + (l & 15);
        float cc = cv[col];
        #pragma unroll
        for (int r = 0; r < 4; ++r){
          int row = mf*16 + ((l >> 4) << 2) + r;
          unsigned short h = f2bf(acc2[mf][nf][r] + cc);
          size_t gg = (size_t)(row0 + row);
          if (col < 64) node_l[gg*64 + col] = h;
          else          node_r[gg*64 + col - 64] = h;
        }
      }
  } else {
    // ---------- rel path ----------
    int rb = g*3 + (r5 - 2);
    if (rb >= REL_BLKS) return;
    int row0 = rb * 64;
    {
      const float4* Rg = (const float4*)relE;
      #pragma unroll
      for (int it = 0; it < 16; ++it){
        int f = tid + 256*it;
        int r = f >> 6, c4 = f & 63;
        int ge = row0 + r; if (ge >= N_EDGES) ge = N_EDGES-1;
        float4 v = Rg[(size_t)ge*64 + c4];
        uint2 u;
        u.x = pk2bf(v.x, v.y);
        u.y = pk2bf(v.z, v.w);
        int byte = (r << 9) + (c4 << 3);
        byte ^= (r & 7) << 4;
        *(uint2*)(smem + byte) = u;
      }
    }
    __syncthreads();
    f32x4 acc[4][2];
    #pragma unroll
    for (int mf = 0; mf < 4; ++mf){ acc[mf][0] = (f32x4){0.f,0.f,0.f,0.f}; acc[mf][1] = (f32x4){0.f,0.f,0.f,0.f}; }
    for (int kb = 0; kb < 8; ++kb){
      bf16x8 a[4], b0, b1;
      #pragma unroll
      for (int mf = 0; mf < 4; ++mf){
        int row = mf*16 + (l & 15);
        int byte = (row << 9) + kb*64 + ((l >> 4) << 4);
        byte ^= (row & 7) << 4;
        a[mf] = *(const bf16x8*)(smem + byte);
      }
      b0 = *(const bf16x8*)(Wr_pk + ((size_t)(wn*8 + kb)*64 + l)*8);        // left  nb=wn
      b1 = *(const bf16x8*)(Wr_pk + ((size_t)((4+wn)*8 + kb)*64 + l)*8);    // right nb=4+wn
      #pragma unroll
      for (int mf = 0; mf < 4; ++mf){
        acc[mf][0] = __builtin_amdgcn_mfma_f32_16x16x32_bf16(a[mf], b0, acc[mf][0], 0, 0, 0);
        acc[mf][1] = __builtin_amdgcn_mfma_f32_16x16x32_bf16(a[mf], b1, acc[mf][1], 0, 0, 0);
      }
    }
    int c = wn*16 + (l & 15);
    float cvL = cv[128 + c], cvR = cv[192 + c];
    #pragma unroll
    for (int mf = 0; mf < 4; ++mf)
      #pragma unroll
      for (int r = 0; r < 4; ++r){
        int row = mf*16 + ((l >> 4) << 2) + r;
        int e = row0 + row;
        if (e < N_EDGES)
          rel_pk[(size_t)e*64 + c] = pk2bf(acc[mf][0][r] + cvL, acc[mf][1][r] + cvR);
      }
  }
}

// ---------------- edge scoring (compose + GEMM2 + logit), barrier-free ----------------
// 64 edges/block, 4 waves; wave owns 16 edges. Front-loads 16 packed-rel uints
// + 32 node gathers (one stall/wave); 4KB wave-private LDS; high occupancy.
__global__ __launch_bounds__(256, 4) void k_score(const unsigned* __restrict__ rel_pk,
    const unsigned short* __restrict__ Wc_pk, const float* __restrict__ bc,
    const unsigned short* __restrict__ node_l, const unsigned short* __restrict__ node_r,
    const unsigned* __restrict__ qctx_p,
    const int* __restrict__ src, const int* __restrict__ dst, const int* __restrict__ eg,
    float* __restrict__ exbuf, float* __restrict__ denom){
  __shared__ char smem[16384];
  int tid = threadIdx.x;
  int l = tid & 63, wn = tid >> 6;
  char* wbase = smem + wn*4096;
  char* sLc  = wbase;            // [16][64] bf16, swz (row&12)<<3  (2KB)
  char* sRin = wbase + 2048;     // [16][64] bf16, swz (row&7)<<4   (2KB)
  int e0 = blockIdx.x * 64 + wn*16;

  // (1) index load: lanes 0-15 src, 16-31 dst, 32-47 eg
  int idxv;
  {
    int j = l & 15;
    int e = e0 + j;
    int ec = e < N_EDGES ? e : N_EDGES-1;
    const int* p = (l < 16) ? src : (l < 32) ? dst : eg;
    idxv = p[ec];
  }
  // (2) front-load: rel rows (coalesced, L3-hot) + node gathers
  unsigned rlrv[16];
  unsigned short nlv[16], nrv[16];
  #pragma unroll
  for (int j = 0; j < 16; ++j){
    int e = e0 + j;
    int ec = e < N_EDGES ? e : N_EDGES-1;
    rlrv[j] = rel_pk[(size_t)ec*64 + l];
    int s  = __shfl(idxv, j);
    int d2 = __shfl(idxv, 16 + j);
    nlv[j] = node_l[(size_t)s*64 + l];
    nrv[j] = node_r[(size_t)d2*64 + l];
  }
  // (3) compose -> sLc/sRin (wave-local)
  #pragma unroll
  for (int j = 0; j < 16; ++j){
    int e = e0 + j;
    int bL = (j << 7) + (l << 1);  bL ^= (j & 12) << 3;
    int bR = (j << 7) + (l << 1);  bR ^= (j & 7) << 4;
    unsigned short lh16 = 0, rr16 = 0;
    if (e < N_EDGES){
      int b = __shfl(idxv, 32 + j);
      unsigned qv = qctx_p[b*64 + l];
      unsigned rv = rlrv[j];
      float lh = leaky(bf2f(nlv[j]) + bf2f((unsigned short)(rv & 0xFFFFu))
                       + bf2f((unsigned short)(qv & 0xFFFFu)));
      float rr = leaky(bf2f(nrv[j]) + bf2f((unsigned short)(rv >> 16))
                       + bf2f((unsigned short)(qv >> 16)));
      lh16 = f2bf(lh); rr16 = f2bf(rr);
    }
    *(unsigned short*)(sLc + bL) = lh16;
    *(unsigned short*)(sRin + bR) = rr16;
  }
  // (4) GEMM2: RH[16][64] = sRin @ Wc (wave-local)
  float bcv[4];
  #pragma unroll
  for (int nf = 0; nf < 4; ++nf) bcv[nf] = bc[nf*16 + (l & 15)];
  f32x4 acc2[4];
  #pragma unroll
  for (int nf = 0; nf < 4; ++nf) acc2[nf] = (f32x4){0.f,0.f,0.f,0.f};
  #pragma unroll
  for (int kb = 0; kb < 2; ++kb){
    int row = l & 15;
    int byte = (row << 7) + kb*64 + ((l >> 4) << 4);
    byte ^= (row & 7) << 4;
    bf16x8 a = *(const bf16x8*)(sRin + byte);
    #pragma unroll
    for (int nf = 0; nf < 4; ++nf){
      bf16x8 bfr = *(const bf16x8*)(Wc_pk + ((size_t)(nf*2 + kb)*64 + l)*8);
      acc2[nf] = __builtin_amdgcn_mfma_f32_16x16x32_bf16(a, bfr, acc2[nf], 0, 0, 0);
    }
  }
  // (5) logit = sum_col (RH+bc)*lh, 16-lane-group reduce; tail: exp + denom atomic
  int srcj[4];
  float vr[4];
  #pragma unroll
  for (int r = 0; r < 4; ++r){
    int rowl = ((l >> 4) << 2) + r;
    srcj[r] = __shfl(idxv, rowl);
    float v = 0.f;
    #pragma unroll
    for (int nf = 0; nf < 4; ++nf){
      int col = nf*16 + (l & 15);
      int byte = (rowl << 7) + (col << 1);
      byte ^= (rowl & 12) << 3;
      v += (acc2[nf][r] + bcv[nf]) * bf2f(*(unsigned short*)(sLc + byte));
    }
    v += __shfl_xor(v, 1); v += __shfl_xor(v, 2);
    v += __shfl_xor(v, 4); v += __shfl_xor(v, 8);
    vr[r] = v;
  }
  if ((l & 15) == 0){
    #pragma unroll
    for (int r = 0; r < 4; ++r){
      int rowl = ((l >> 4) << 2) + r;
      int e = e0 + rowl;
      if (e < N_EDGES){
        float ex = __expf(vr[r]);
        exbuf[e] = ex;
        atomicAdd(&denom[srcj[r]], ex);
      }
    }
  }
}

// ---------------- final pass: trans + propagate + entity aggregate ----------------
__global__ void k_passC(const float* __restrict__ exbuf, const float* __restrict__ denom,
                        const int* __restrict__ src, const int* __restrict__ dst,
                        const float* __restrict__ node_score, const int* __restrict__ ent,
                        float* __restrict__ out){
  int e = blockIdx.x*256 + threadIdx.x;
  if (e >= N_EDGES) return;
  int s = src[e];
  float tr = exbuf[e] / denom[s];
  atomicAdd(&out[ent[dst[e]]], tr * node_score[s]);
}

// ---------------- host ----------------
extern "C" void kernel_launch(void* const* d_in, const int* in_sizes, int n_in,
                              void* d_out, int out_size, void* d_ws, size_t ws_size,
                              hipStream_t stream){
  const float* mem   = (const float*)d_in[0];
  const float* nsc   = (const float*)d_in[1];
  const float* relE  = (const float*)d_in[2];
  const float* qsrc  = (const float*)d_in[3];
  const float* qrel  = (const float*)d_in[4];
  const int*   eg    = (const int*)d_in[5];
  const int*   src   = (const int*)d_in[6];
  const int*   dst   = (const int*)d_in[7];
  const int*   ent   = (const int*)d_in[8];
  const float* Wp    = (const float*)d_in[9];
  const float* bp    = (const float*)d_in[10];
  const float* Ws    = (const float*)d_in[11];
  const float* bs    = (const float*)d_in[12];
  const float* Wbs   = (const float*)d_in[13];
  const float* bbs   = (const float*)d_in[14];
  const float* Wl    = (const float*)d_in[15];
  const float* bl    = (const float*)d_in[16];
  const float* Wr    = (const float*)d_in[17];
  const float* br    = (const float*)d_in[18];
  const float* Wc    = (const float*)d_in[19];
  const float* bc    = (const float*)d_in[20];
  float* out = (float*)d_out;

  char* w = (char*)d_ws;
  auto alloc = [&](size_t bytes)->void*{
    void* p = (void*)w; w += (bytes + 255) & ~(size_t)255; return p;
  };
  float* Wnlr = (float*)alloc(32768*4);
  float* Wrlr = (float*)alloc(32768*4);
  unsigned short* Wbs_pk = (unsigned short*)alloc(65536*2);
  unsigned short* Wn_pk  = (unsigned short*)alloc(32768*2);
  unsigned short* Wr_pk  = (unsigned short*)alloc(32768*2);
  unsigned short* Wc_pk  = (unsigned short*)alloc(4096*2);
  float* cv  = (float*)alloc(256*4);
  float* qs  = (float*)alloc((size_t)N_Q*SSM*4);
  float* qr  = (float*)alloc((size_t)N_Q*DSM*4);
  unsigned* qctx_p = (unsigned*)alloc((size_t)N_Q*DSM*4);
  unsigned short* node_l = (unsigned short*)alloc((size_t)N_NODES*64*2);
  unsigned short* node_r = (unsigned short*)alloc((size_t)N_NODES*64*2);
  unsigned* rel_pk = (unsigned*)alloc((size_t)N_EDGES*64*4);
  float* exbuf  = (float*)alloc((size_t)N_EDGES*4);
  float* denom = (float*)alloc((size_t)N_NODES*4);

  k_setup1<<<1121, 256, 0, stream>>>(out, denom,
                                     Wp, Wl, Wr, Wnlr, Wrlr, bp, cv,
                                     qsrc, Ws, bs, qrel, qs, qr,
                                     Wbs, Wbs_pk, Wc, Wc_pk);
  k_setup2<<<64, 256, 0, stream>>>(qs, qr, Wl, bl, Wr, br, qctx_p,
                                   Wnlr, Wn_pk, Wrlr, Wr_pk);
  k_proj<<<1563*5, 256, 0, stream>>>(mem, Wbs_pk, bbs, Wn_pk, cv, node_l, node_r,
                                     relE, Wr_pk, rel_pk);
  k_score<<<(N_EDGES+63)/64, 256, 0, stream>>>(rel_pk, Wc_pk, bc, node_l, node_r, qctx_p,
                                               src, dst, eg, exbuf, denom);
  k_passC<<<(N_EDGES+255)/256, 256, 0, stream>>>(exbuf, denom, src, dst, nsc, ent, out);
}

// Round 17
// 229.455 us; speedup vs baseline: 1.5627x; 1.0078x over previous
//
#include <hip/hip_runtime.h>
#include <hip/hip_bf16.h>

#define N_NODES 200000
#define N_EDGES 300000
#define N_Q     128
#define N_ENT   50000
#define D       256
#define DSM     64
#define SDIM    128
#define SSM     32

#define NODE_BLKS 3125
#define REL_BLKS  4688

typedef __attribute__((ext_vector_type(8))) short bf16x8;
typedef __attribute__((ext_vector_type(4))) float f32x4;

__device__ __forceinline__ float leaky(float x){ return x > 0.f ? x : 0.01f*x; }

__device__ __forceinline__ unsigned short f2bf(float f){
  __hip_bfloat16 h = __float2bfloat16(f);
  return *reinterpret_cast<unsigned short*>(&h);
}
__device__ __forceinline__ unsigned pk2bf(float a, float b){
  float2 t; t.x = a; t.y = b;
  __hip_bfloat162 h = __float22bfloat162_rn(t);
  return *reinterpret_cast<unsigned*>(&h);
}
__device__ __forceinline__ float bf2f(unsigned short h){
  return __uint_as_float(((unsigned)h) << 16);
}

// pack fp32 [K][N] row-major -> bf16 MFMA B-fragment order.
__device__ __forceinline__ void dev_pack(const float* __restrict__ src,
                                         unsigned short* __restrict__ dst,
                                         int K, int N, int id, int total){
  if (id >= total) return;
  int lane = id & 63, fb = id >> 6;
  int KB = K >> 5;
  int kb = fb % KB, nb = fb / KB;
  int k0 = kb*32 + ((lane>>4)<<3);
  int n  = nb*16 + (lane & 15);
  #pragma unroll
  for (int i = 0; i < 8; ++i) dst[(size_t)id*8 + i] = f2bf(src[(size_t)(k0+i)*N + n]);
}

// ---------------- single fused setup kernel ----------------
// blocks: [0,128) qctx per query (self-contained) | [128,384) fold Wl/Wr -> packed
//         [384,416) pack Wbs | [416,418) pack Wc | 418 foldb cv
__global__ void k_setup(const float* __restrict__ Wp, const float* __restrict__ Wl,
                        const float* __restrict__ Wr, const float* __restrict__ bp,
                        float* cv,
                        const float* __restrict__ qsrc, const float* __restrict__ Ws,
                        const float* __restrict__ bs, const float* __restrict__ qrel,
                        const float* __restrict__ bl, const float* __restrict__ br,
                        unsigned* qctx_p,
                        const float* __restrict__ Wbs, unsigned short* Wbs_pk,
                        unsigned short* Wn_pk, unsigned short* Wr_pk,
                        const float* __restrict__ Wc, unsigned short* Wc_pk){
  int b = blockIdx.x, tid = threadIdx.x;
  if (b < 128){
    // per-query qctx: stage query row, compute qs/qr in-block, then qctx
    __shared__ float qrow[384];      // [0:128) qsrc row, [128:384) qrel row
    __shared__ float qs_s[32];
    __shared__ float qr_s[64];
    int q = b;
    if (tid < 128) qrow[tid] = qsrc[q*SDIM + tid];
    qrow[128 + tid] = qrel[q*D + tid];
    __syncthreads();
    if (tid < 32){
      float s = bs[tid];
      for (int j = 0; j < SDIM; ++j) s += qrow[j] * Ws[j*SSM + tid];
      qs_s[tid] = s;
    } else if (tid < 96){
      int i = tid - 32;
      float s = bp[i];
      for (int j = 0; j < D; ++j) s += qrow[128 + j] * Wp[j*DSM + i];
      qr_s[i] = s;
    }
    __syncthreads();
    if (tid < 64){
      int c = tid;
      float sl = bl[c], sr = br[c];
      for (int i = 0; i < SSM; ++i){
        float v = qs_s[i];
        sl += v * Wl[(128+i)*64 + c];
        sr += v * Wr[(128+i)*64 + c];
      }
      for (int i = 0; i < DSM; ++i){
        float v = qr_s[i];
        sl += v * Wl[(160+i)*64 + c];
        sr += v * Wr[(160+i)*64 + c];
      }
      qctx_p[q*64 + c] = pk2bf(sl, sr);
    }
  } else if (b < 384){
    // fold Wp @ Wl/Wr slices, write DIRECTLY into packed bf16 fragment order
    int id = (b-128)*256 + tid;       // 65536
    int m = id >> 14, rem = id & 16383, k = rem >> 6, c = rem & 63;
    const float* Wsrc = (m & 1) ? Wr : Wl;
    int roff = (m >> 1) * 64;
    float s = 0.f;
    for (int i = 0; i < 64; ++i) s += Wp[k*64+i] * Wsrc[(roff+i)*64 + c];
    int n = (m & 1)*64 + c;           // col in [K=256][N=128] folded matrix
    int kb = k >> 5, hi = (k >> 3) & 3, i8 = k & 7;
    int nb = n >> 4, lane = hi*16 + (n & 15);
    size_t idx = ((size_t)(nb*8 + kb)*64 + lane)*8 + i8;
    unsigned short* dst = (m >> 1) ? Wr_pk : Wn_pk;
    dst[idx] = f2bf(s);
  } else if (b < 416){
    dev_pack(Wbs, Wbs_pk, 256, 256, (b-384)*256 + tid, 8192);
  } else if (b < 418){
    dev_pack(Wc, Wc_pk, 64, 64, (b-416)*256 + tid, 512);
  } else {
    int m = tid >> 6, c = tid & 63;
    const float* Wsrc = (m & 1) ? Wr : Wl;
    int roff = (m >> 1) * 64;
    float s = 0.f;
    for (int i = 0; i < 64; ++i) s += bp[i] * Wsrc[(roff+i)*64 + c];
    cv[tid] = s;
  }
}

// ---------------- fused projection kernel: node GEMM + rel GEMM interleaved ----------------
// Groups of 5 blocks: 2 node-blocks + 3 rel-blocks (ratio 3125:4688). Prologue
// zeroes out/denom (consumed only by later kernels; stream order guarantees
// completion). Body identical to the validated R11/R16 kernel.
__global__ __launch_bounds__(256) void k_proj(const float* __restrict__ A,
    const unsigned short* __restrict__ Wbs_pk, const float* __restrict__ bbs,
    const unsigned short* __restrict__ Wn_pk, const float* __restrict__ cv,
    unsigned short* __restrict__ node_l, unsigned short* __restrict__ node_r,
    const float* __restrict__ relE, const unsigned short* __restrict__ Wr_pk,
    unsigned* __restrict__ rel_pk,
    float* __restrict__ out_z, float* __restrict__ denom_z){
  __shared__ char smem[32768];
  int tid = threadIdx.x;
  // zero prologue (2M threads cover 250k elements)
  {
    int id = blockIdx.x*256 + tid;
    if (id < N_ENT) out_z[id] = 0.f;
    if (id < N_NODES) denom_z[id] = 0.f;
  }
  int l = tid & 63, wn = tid >> 6;
  int g = blockIdx.x / 5, r5 = blockIdx.x % 5;

  if (r5 < 2){
    // ---------- node path ----------
    int nb = g*2 + r5;
    if (nb >= NODE_BLKS) return;
    int row0 = nb * 64;
    {
      const float4* Ag = (const float4*)(A + (size_t)row0 * 256);
      #pragma unroll
      for (int it = 0; it < 16; ++it){
        int f = tid + 256*it;
        int r = f >> 6, c4 = f & 63;
        float4 v = Ag[f];
        uint2 u;
        u.x = pk2bf(v.x, v.y);
        u.y = pk2bf(v.z, v.w);
        int byte = (r << 9) + (c4 << 3);
        byte ^= (r & 7) << 4;
        *(uint2*)(smem + byte) = u;
      }
    }
    __syncthreads();
    f32x4 acc[4][4];
    #pragma unroll
    for (int mf = 0; mf < 4; ++mf)
      #pragma unroll
      for (int nf = 0; nf < 4; ++nf) acc[mf][nf] = (f32x4){0.f,0.f,0.f,0.f};
    for (int kb = 0; kb < 8; ++kb){
      bf16x8 a[4], b[4];
      #pragma unroll
      for (int mf = 0; mf < 4; ++mf){
        int row = mf*16 + (l & 15);
        int byte = (row << 9) + kb*64 + ((l >> 4) << 4);
        byte ^= (row & 7) << 4;
        a[mf] = *(const bf16x8*)(smem + byte);
      }
      #pragma unroll
      for (int nf = 0; nf < 4; ++nf){
        int nbb = wn*4 + nf;
        b[nf] = *(const bf16x8*)(Wbs_pk + ((size_t)(nbb*8 + kb)*64 + l)*8);
      }
      #pragma unroll
      for (int mf = 0; mf < 4; ++mf)
        #pragma unroll
        for (int nf = 0; nf < 4; ++nf)
          acc[mf][nf] = __builtin_amdgcn_mfma_f32_16x16x32_bf16(a[mf], b[nf], acc[mf][nf], 0, 0, 0);
    }
    __syncthreads();
    #pragma unroll
    for (int mf = 0; mf < 4; ++mf)
      #pragma unroll
      for (int nf = 0; nf < 4; ++nf){
        int col = wn*64 + nf*16 + (l & 15);
        float bb = bbs[col];
        #pragma unroll
        for (int r = 0; r < 4; ++r){
          int row = mf*16 + ((l >> 4) << 2) + r;
          int byte = (row << 9) + col*2;
          byte ^= (row & 7) << 4;
          *(unsigned short*)(smem + byte) = f2bf(leaky(acc[mf][nf][r] + bb));
        }
      }
    __syncthreads();
    f32x4 acc2[4][2];
    #pragma unroll
    for (int mf = 0; mf < 4; ++mf){ acc2[mf][0] = (f32x4){0.f,0.f,0.f,0.f}; acc2[mf][1] = (f32x4){0.f,0.f,0.f,0.f}; }
    for (int kb = 0; kb < 8; ++kb){
      bf16x8 a[4], b[2];
      #pragma unroll
      for (int mf = 0; mf < 4; ++mf){
        int row = mf*16 + (l & 15);
        int byte = (row << 9) + kb*64 + ((l >> 4) << 4);
        byte ^= (row & 7) << 4;
        a[mf] = *(const bf16x8*)(smem + byte);
      }
      #pragma unroll
      for (int nf = 0; nf < 2; ++nf){
        int nbb = wn*2 + nf;
        b[nf] = *(const bf16x8*)(Wn_pk + ((size_t)(nbb*8 + kb)*64 + l)*8);
      }
      #pragma unroll
      for (int mf = 0; mf < 4; ++mf)
        #pragma unroll
        for (int nf = 0; nf < 2; ++nf)
          acc2[mf][nf] = __builtin_amdgcn_mfma_f32_16x16x32_bf16(a[mf], b[nf], acc2[mf][nf], 0, 0, 0);
    }
    #pragma unroll
    for (int mf = 0; mf < 4; ++mf)
      #pragma unroll
      for (int nf = 0; nf < 2; ++nf){
        int col = wn*32 + nf*16 + (l & 15);
        float cc = cv[col];
        #pragma unroll
        for (int r = 0; r < 4; ++r){
          int row = mf*16 + ((l >> 4) << 2) + r;
          unsigned short h = f2bf(acc2[mf][nf][r] + cc);
          size_t gg = (size_t)(row0 + row);
          if (col < 64) node_l[gg*64 + col] = h;
          else          node_r[gg*64 + col - 64] = h;
        }
      }
  } else {
    // ---------- rel path ----------
    int rb = g*3 + (r5 - 2);
    if (rb >= REL_BLKS) return;
    int row0 = rb * 64;
    {
      const float4* Rg = (const float4*)relE;
      #pragma unroll
      for (int it = 0; it < 16; ++it){
        int f = tid + 256*it;
        int r = f >> 6, c4 = f & 63;
        int ge = row0 + r; if (ge >= N_EDGES) ge = N_EDGES-1;
        float4 v = Rg[(size_t)ge*64 + c4];
        uint2 u;
        u.x = pk2bf(v.x, v.y);
        u.y = pk2bf(v.z, v.w);
        int byte = (r << 9) + (c4 << 3);
        byte ^= (r & 7) << 4;
        *(uint2*)(smem + byte) = u;
      }
    }
    __syncthreads();
    f32x4 acc[4][2];
    #pragma unroll
    for (int mf = 0; mf < 4; ++mf){ acc[mf][0] = (f32x4){0.f,0.f,0.f,0.f}; acc[mf][1] = (f32x4){0.f,0.f,0.f,0.f}; }
    for (int kb = 0; kb < 8; ++kb){
      bf16x8 a[4], b0, b1;
      #pragma unroll
      for (int mf = 0; mf < 4; ++mf){
        int row = mf*16 + (l & 15);
        int byte = (row << 9) + kb*64 + ((l >> 4) << 4);
        byte ^= (row & 7) << 4;
        a[mf] = *(const bf16x8*)(smem + byte);
      }
      b0 = *(const bf16x8*)(Wr_pk + ((size_t)(wn*8 + kb)*64 + l)*8);        // left  nb=wn
      b1 = *(const bf16x8*)(Wr_pk + ((size_t)((4+wn)*8 + kb)*64 + l)*8);    // right nb=4+wn
      #pragma unroll
      for (int mf = 0; mf < 4; ++mf){
        acc[mf][0] = __builtin_amdgcn_mfma_f32_16x16x32_bf16(a[mf], b0, acc[mf][0], 0, 0, 0);
        acc[mf][1] = __builtin_amdgcn_mfma_f32_16x16x32_bf16(a[mf], b1, acc[mf][1], 0, 0, 0);
      }
    }
    int c = wn*16 + (l & 15);
    float cvL = cv[128 + c], cvR = cv[192 + c];
    #pragma unroll
    for (int mf = 0; mf < 4; ++mf)
      #pragma unroll
      for (int r = 0; r < 4; ++r){
        int row = mf*16 + ((l >> 4) << 2) + r;
        int e = row0 + row;
        if (e < N_EDGES)
          rel_pk[(size_t)e*64 + c] = pk2bf(acc[mf][0][r] + cvL, acc[mf][1][r] + cvR);
      }
  }
}

// ---------------- edge scoring (compose + GEMM2 + logit), barrier-free ----------------
__global__ __launch_bounds__(256, 4) void k_score(const unsigned* __restrict__ rel_pk,
    const unsigned short* __restrict__ Wc_pk, const float* __restrict__ bc,
    const unsigned short* __restrict__ node_l, const unsigned short* __restrict__ node_r,
    const unsigned* __restrict__ qctx_p,
    const int* __restrict__ src, const int* __restrict__ dst, const int* __restrict__ eg,
    float* __restrict__ exbuf, float* __restrict__ denom){
  __shared__ char smem[16384];
  int tid = threadIdx.x;
  int l = tid & 63, wn = tid >> 6;
  char* wbase = smem + wn*4096;
  char* sLc  = wbase;            // [16][64] bf16, swz (row&12)<<3  (2KB)
  char* sRin = wbase + 2048;     // [16][64] bf16, swz (row&7)<<4   (2KB)
  int e0 = blockIdx.x * 64 + wn*16;

  int idxv;
  {
    int j = l & 15;
    int e = e0 + j;
    int ec = e < N_EDGES ? e : N_EDGES-1;
    const int* p = (l < 16) ? src : (l < 32) ? dst : eg;
    idxv = p[ec];
  }
  unsigned rlrv[16];
  unsigned short nlv[16], nrv[16];
  #pragma unroll
  for (int j = 0; j < 16; ++j){
    int e = e0 + j;
    int ec = e < N_EDGES ? e : N_EDGES-1;
    rlrv[j] = rel_pk[(size_t)ec*64 + l];
    int s  = __shfl(idxv, j);
    int d2 = __shfl(idxv, 16 + j);
    nlv[j] = node_l[(size_t)s*64 + l];
    nrv[j] = node_r[(size_t)d2*64 + l];
  }
  #pragma unroll
  for (int j = 0; j < 16; ++j){
    int e = e0 + j;
    int bL = (j << 7) + (l << 1);  bL ^= (j & 12) << 3;
    int bR = (j << 7) + (l << 1);  bR ^= (j & 7) << 4;
    unsigned short lh16 = 0, rr16 = 0;
    if (e < N_EDGES){
      int b = __shfl(idxv, 32 + j);
      unsigned qv = qctx_p[b*64 + l];
      unsigned rv = rlrv[j];
      float lh = leaky(bf2f(nlv[j]) + bf2f((unsigned short)(rv & 0xFFFFu))
                       + bf2f((unsigned short)(qv & 0xFFFFu)));
      float rr = leaky(bf2f(nrv[j]) + bf2f((unsigned short)(rv >> 16))
                       + bf2f((unsigned short)(qv >> 16)));
      lh16 = f2bf(lh); rr16 = f2bf(rr);
    }
    *(unsigned short*)(sLc + bL) = lh16;
    *(unsigned short*)(sRin + bR) = rr16;
  }
  float bcv[4];
  #pragma unroll
  for (int nf = 0; nf < 4; ++nf) bcv[nf] = bc[nf*16 + (l & 15)];
  f32x4 acc2[4];
  #pragma unroll
  for (int nf = 0; nf < 4; ++nf) acc2[nf] = (f32x4){0.f,0.f,0.f,0.f};
  #pragma unroll
  for (int kb = 0; kb < 2; ++kb){
    int row = l & 15;
    int byte = (row << 7) + kb*64 + ((l >> 4) << 4);
    byte ^= (row & 7) << 4;
    bf16x8 a = *(const bf16x8*)(sRin + byte);
    #pragma unroll
    for (int nf = 0; nf < 4; ++nf){
      bf16x8 bfr = *(const bf16x8*)(Wc_pk + ((size_t)(nf*2 + kb)*64 + l)*8);
      acc2[nf] = __builtin_amdgcn_mfma_f32_16x16x32_bf16(a, bfr, acc2[nf], 0, 0, 0);
    }
  }
  int srcj[4];
  float vr[4];
  #pragma unroll
  for (int r = 0; r < 4; ++r){
    int rowl = ((l >> 4) << 2) + r;
    srcj[r] = __shfl(idxv, rowl);
    float v = 0.f;
    #pragma unroll
    for (int nf = 0; nf < 4; ++nf){
      int col = nf*16 + (l & 15);
      int byte = (rowl << 7) + (col << 1);
      byte ^= (rowl & 12) << 3;
      v += (acc2[nf][r] + bcv[nf]) * bf2f(*(unsigned short*)(sLc + byte));
    }
    v += __shfl_xor(v, 1); v += __shfl_xor(v, 2);
    v += __shfl_xor(v, 4); v += __shfl_xor(v, 8);
    vr[r] = v;
  }
  if ((l & 15) == 0){
    #pragma unroll
    for (int r = 0; r < 4; ++r){
      int rowl = ((l >> 4) << 2) + r;
      int e = e0 + rowl;
      if (e < N_EDGES){
        float ex = __expf(vr[r]);
        exbuf[e] = ex;
        atomicAdd(&denom[srcj[r]], ex);
      }
    }
  }
}

// ---------------- final pass: trans + propagate + entity aggregate ----------------
__global__ void k_passC(const float* __restrict__ exbuf, const float* __restrict__ denom,
                        const int* __restrict__ src, const int* __restrict__ dst,
                        const float* __restrict__ node_score, const int* __restrict__ ent,
                        float* __restrict__ out){
  int e = blockIdx.x*256 + threadIdx.x;
  if (e >= N_EDGES) return;
  int s = src[e];
  float tr = exbuf[e] / denom[s];
  atomicAdd(&out[ent[dst[e]]], tr * node_score[s]);
}

// ---------------- host ----------------
extern "C" void kernel_launch(void* const* d_in, const int* in_sizes, int n_in,
                              void* d_out, int out_size, void* d_ws, size_t ws_size,
                              hipStream_t stream){
  const float* mem   = (const float*)d_in[0];
  const float* nsc   = (const float*)d_in[1];
  const float* relE  = (const float*)d_in[2];
  const float* qsrc  = (const float*)d_in[3];
  const float* qrel  = (const float*)d_in[4];
  const int*   eg    = (const int*)d_in[5];
  const int*   src   = (const int*)d_in[6];
  const int*   dst   = (const int*)d_in[7];
  const int*   ent   = (const int*)d_in[8];
  const float* Wp    = (const float*)d_in[9];
  const float* bp    = (const float*)d_in[10];
  const float* Ws    = (const float*)d_in[11];
  const float* bs    = (const float*)d_in[12];
  const float* Wbs   = (const float*)d_in[13];
  const float* bbs   = (const float*)d_in[14];
  const float* Wl    = (const float*)d_in[15];
  const float* bl    = (const float*)d_in[16];
  const float* Wr    = (const float*)d_in[17];
  const float* br    = (const float*)d_in[18];
  const float* Wc    = (const float*)d_in[19];
  const float* bc    = (const float*)d_in[20];
  float* out = (float*)d_out;

  char* w = (char*)d_ws;
  auto alloc = [&](size_t bytes)->void*{
    void* p = (void*)w; w += (bytes + 255) & ~(size_t)255; return p;
  };
  unsigned short* Wbs_pk = (unsigned short*)alloc(65536*2);
  unsigned short* Wn_pk  = (unsigned short*)alloc(32768*2);
  unsigned short* Wr_pk  = (unsigned short*)alloc(32768*2);
  unsigned short* Wc_pk  = (unsigned short*)alloc(4096*2);
  float* cv  = (float*)alloc(256*4);
  unsigned* qctx_p = (unsigned*)alloc((size_t)N_Q*DSM*4);
  unsigned short* node_l = (unsigned short*)alloc((size_t)N_NODES*64*2);
  unsigned short* node_r = (unsigned short*)alloc((size_t)N_NODES*64*2);
  unsigned* rel_pk = (unsigned*)alloc((size_t)N_EDGES*64*4);
  float* exbuf  = (float*)alloc((size_t)N_EDGES*4);
  float* denom = (float*)alloc((size_t)N_NODES*4);

  k_setup<<<419, 256, 0, stream>>>(Wp, Wl, Wr, bp, cv,
                                   qsrc, Ws, bs, qrel, bl, br, qctx_p,
                                   Wbs, Wbs_pk, Wn_pk, Wr_pk, Wc, Wc_pk);
  k_proj<<<1563*5, 256, 0, stream>>>(mem, Wbs_pk, bbs, Wn_pk, cv, node_l, node_r,
                                     relE, Wr_pk, rel_pk, out, denom);
  k_score<<<(N_EDGES+63)/64, 256, 0, stream>>>(rel_pk, Wc_pk, bc, node_l, node_r, qctx_p,
                                               src, dst, eg, exbuf, denom);
  k_passC<<<(N_EDGES+255)/256, 256, 0, stream>>>(exbuf, denom, src, dst, nsc, ent, out);
}

// Round 19
// 224.471 us; speedup vs baseline: 1.5974x; 1.0222x over previous
//
#include <hip/hip_runtime.h>
#include <hip/hip_bf16.h>

#define N_NODES 200000
#define N_EDGES 300000
#define N_Q     128
#define N_ENT   50000
#define D       256
#define DSM     64
#define SDIM    128
#define SSM     32

#define NODE_BLKS 3125
#define REL_BLKS  4688

typedef __attribute__((ext_vector_type(8))) short bf16x8;
typedef __attribute__((ext_vector_type(4))) float f32x4;
typedef __attribute__((ext_vector_type(4))) float fvec4;   // builtin-compatible float4

__device__ __forceinline__ float leaky(float x){ return x > 0.f ? x : 0.01f*x; }

__device__ __forceinline__ unsigned short f2bf(float f){
  __hip_bfloat16 h = __float2bfloat16(f);
  return *reinterpret_cast<unsigned short*>(&h);
}
__device__ __forceinline__ unsigned pk2bf(float a, float b){
  float2 t; t.x = a; t.y = b;
  __hip_bfloat162 h = __float22bfloat162_rn(t);
  return *reinterpret_cast<unsigned*>(&h);
}
__device__ __forceinline__ float bf2f(unsigned short h){
  return __uint_as_float(((unsigned)h) << 16);
}

// pack fp32 [K][N] row-major -> bf16 MFMA B-fragment order.
__device__ __forceinline__ void dev_pack(const float* __restrict__ src,
                                         unsigned short* __restrict__ dst,
                                         int K, int N, int id, int total){
  if (id >= total) return;
  int lane = id & 63, fb = id >> 6;
  int KB = K >> 5;
  int kb = fb % KB, nb = fb / KB;
  int k0 = kb*32 + ((lane>>4)<<3);
  int n  = nb*16 + (lane & 15);
  #pragma unroll
  for (int i = 0; i < 8; ++i) dst[(size_t)id*8 + i] = f2bf(src[(size_t)(k0+i)*N + n]);
}

// ---------------- single fused setup kernel ----------------
__global__ void k_setup(const float* __restrict__ Wp, const float* __restrict__ Wl,
                        const float* __restrict__ Wr, const float* __restrict__ bp,
                        float* cv,
                        const float* __restrict__ qsrc, const float* __restrict__ Ws,
                        const float* __restrict__ bs, const float* __restrict__ qrel,
                        const float* __restrict__ bl, const float* __restrict__ br,
                        unsigned* qctx_p,
                        const float* __restrict__ Wbs, unsigned short* Wbs_pk,
                        unsigned short* Wn_pk, unsigned short* Wr_pk,
                        const float* __restrict__ Wc, unsigned short* Wc_pk){
  int b = blockIdx.x, tid = threadIdx.x;
  if (b < 128){
    __shared__ float qrow[384];
    __shared__ float qs_s[32];
    __shared__ float qr_s[64];
    int q = b;
    if (tid < 128) qrow[tid] = qsrc[q*SDIM + tid];
    qrow[128 + tid] = qrel[q*D + tid];
    __syncthreads();
    if (tid < 32){
      float s = bs[tid];
      for (int j = 0; j < SDIM; ++j) s += qrow[j] * Ws[j*SSM + tid];
      qs_s[tid] = s;
    } else if (tid < 96){
      int i = tid - 32;
      float s = bp[i];
      for (int j = 0; j < D; ++j) s += qrow[128 + j] * Wp[j*DSM + i];
      qr_s[i] = s;
    }
    __syncthreads();
    if (tid < 64){
      int c = tid;
      float sl = bl[c], sr = br[c];
      for (int i = 0; i < SSM; ++i){
        float v = qs_s[i];
        sl += v * Wl[(128+i)*64 + c];
        sr += v * Wr[(128+i)*64 + c];
      }
      for (int i = 0; i < DSM; ++i){
        float v = qr_s[i];
        sl += v * Wl[(160+i)*64 + c];
        sr += v * Wr[(160+i)*64 + c];
      }
      qctx_p[q*64 + c] = pk2bf(sl, sr);
    }
  } else if (b < 384){
    int id = (b-128)*256 + tid;       // 65536
    int m = id >> 14, rem = id & 16383, k = rem >> 6, c = rem & 63;
    const float* Wsrc = (m & 1) ? Wr : Wl;
    int roff = (m >> 1) * 64;
    float s = 0.f;
    for (int i = 0; i < 64; ++i) s += Wp[k*64+i] * Wsrc[(roff+i)*64 + c];
    int n = (m & 1)*64 + c;
    int kb = k >> 5, hi = (k >> 3) & 3, i8 = k & 7;
    int nb = n >> 4, lane = hi*16 + (n & 15);
    size_t idx = ((size_t)(nb*8 + kb)*64 + lane)*8 + i8;
    unsigned short* dst = (m >> 1) ? Wr_pk : Wn_pk;
    dst[idx] = f2bf(s);
  } else if (b < 416){
    dev_pack(Wbs, Wbs_pk, 256, 256, (b-384)*256 + tid, 8192);
  } else if (b < 418){
    dev_pack(Wc, Wc_pk, 64, 64, (b-416)*256 + tid, 512);
  } else {
    int m = tid >> 6, c = tid & 63;
    const float* Wsrc = (m & 1) ? Wr : Wl;
    int roff = (m >> 1) * 64;
    float s = 0.f;
    for (int i = 0; i < 64; ++i) s += bp[i] * Wsrc[(roff+i)*64 + c];
    cv[tid] = s;
  }
}

// ---------------- fused projection kernel: node GEMM + rel GEMM interleaved ----------------
// R17 body + (a) s_setprio(1) around MFMA loops (T5: co-resident blocks are
// phase-diverse, scheduler can favor MFMA-issuing waves), (b) non-temporal
// stage loads (mem/relE are read exactly once; keep L2/L3 for hot weights).
__global__ __launch_bounds__(256) void k_proj(const float* __restrict__ A,
    const unsigned short* __restrict__ Wbs_pk, const float* __restrict__ bbs,
    const unsigned short* __restrict__ Wn_pk, const float* __restrict__ cv,
    unsigned short* __restrict__ node_l, unsigned short* __restrict__ node_r,
    const float* __restrict__ relE, const unsigned short* __restrict__ Wr_pk,
    unsigned* __restrict__ rel_pk,
    float* __restrict__ out_z, float* __restrict__ denom_z){
  __shared__ char smem[32768];
  int tid = threadIdx.x;
  {
    int id = blockIdx.x*256 + tid;
    if (id < N_ENT) out_z[id] = 0.f;
    if (id < N_NODES) denom_z[id] = 0.f;
  }
  int l = tid & 63, wn = tid >> 6;
  int g = blockIdx.x / 5, r5 = blockIdx.x % 5;

  if (r5 < 2){
    // ---------- node path ----------
    int nb = g*2 + r5;
    if (nb >= NODE_BLKS) return;
    int row0 = nb * 64;
    {
      const fvec4* Ag = (const fvec4*)(A + (size_t)row0 * 256);
      #pragma unroll
      for (int it = 0; it < 16; ++it){
        int f = tid + 256*it;
        int r = f >> 6, c4 = f & 63;
        fvec4 v = __builtin_nontemporal_load(&Ag[f]);
        uint2 u;
        u.x = pk2bf(v.x, v.y);
        u.y = pk2bf(v.z, v.w);
        int byte = (r << 9) + (c4 << 3);
        byte ^= (r & 7) << 4;
        *(uint2*)(smem + byte) = u;
      }
    }
    __syncthreads();
    f32x4 acc[4][4];
    #pragma unroll
    for (int mf = 0; mf < 4; ++mf)
      #pragma unroll
      for (int nf = 0; nf < 4; ++nf) acc[mf][nf] = (f32x4){0.f,0.f,0.f,0.f};
    __builtin_amdgcn_s_setprio(1);
    for (int kb = 0; kb < 8; ++kb){
      bf16x8 a[4], b[4];
      #pragma unroll
      for (int mf = 0; mf < 4; ++mf){
        int row = mf*16 + (l & 15);
        int byte = (row << 9) + kb*64 + ((l >> 4) << 4);
        byte ^= (row & 7) << 4;
        a[mf] = *(const bf16x8*)(smem + byte);
      }
      #pragma unroll
      for (int nf = 0; nf < 4; ++nf){
        int nbb = wn*4 + nf;
        b[nf] = *(const bf16x8*)(Wbs_pk + ((size_t)(nbb*8 + kb)*64 + l)*8);
      }
      #pragma unroll
      for (int mf = 0; mf < 4; ++mf)
        #pragma unroll
        for (int nf = 0; nf < 4; ++nf)
          acc[mf][nf] = __builtin_amdgcn_mfma_f32_16x16x32_bf16(a[mf], b[nf], acc[mf][nf], 0, 0, 0);
    }
    __builtin_amdgcn_s_setprio(0);
    __syncthreads();
    #pragma unroll
    for (int mf = 0; mf < 4; ++mf)
      #pragma unroll
      for (int nf = 0; nf < 4; ++nf){
        int col = wn*64 + nf*16 + (l & 15);
        float bb = bbs[col];
        #pragma unroll
        for (int r = 0; r < 4; ++r){
          int row = mf*16 + ((l >> 4) << 2) + r;
          int byte = (row << 9) + col*2;
          byte ^= (row & 7) << 4;
          *(unsigned short*)(smem + byte) = f2bf(leaky(acc[mf][nf][r] + bb));
        }
      }
    __syncthreads();
    f32x4 acc2[4][2];
    #pragma unroll
    for (int mf = 0; mf < 4; ++mf){ acc2[mf][0] = (f32x4){0.f,0.f,0.f,0.f}; acc2[mf][1] = (f32x4){0.f,0.f,0.f,0.f}; }
    __builtin_amdgcn_s_setprio(1);
    for (int kb = 0; kb < 8; ++kb){
      bf16x8 a[4], b[2];
      #pragma unroll
      for (int mf = 0; mf < 4; ++mf){
        int row = mf*16 + (l & 15);
        int byte = (row << 9) + kb*64 + ((l >> 4) << 4);
        byte ^= (row & 7) << 4;
        a[mf] = *(const bf16x8*)(smem + byte);
      }
      #pragma unroll
      for (int nf = 0; nf < 2; ++nf){
        int nbb = wn*2 + nf;
        b[nf] = *(const bf16x8*)(Wn_pk + ((size_t)(nbb*8 + kb)*64 + l)*8);
      }
      #pragma unroll
      for (int mf = 0; mf < 4; ++mf)
        #pragma unroll
        for (int nf = 0; nf < 2; ++nf)
          acc2[mf][nf] = __builtin_amdgcn_mfma_f32_16x16x32_bf16(a[mf], b[nf], acc2[mf][nf], 0, 0, 0);
    }
    __builtin_amdgcn_s_setprio(0);
    #pragma unroll
    for (int mf = 0; mf < 4; ++mf)
      #pragma unroll
      for (int nf = 0; nf < 2; ++nf){
        int col = wn*32 + nf*16 + (l & 15);
        float cc = cv[col];
        #pragma unroll
        for (int r = 0; r < 4; ++r){
          int row = mf*16 + ((l >> 4) << 2) + r;
          unsigned short h = f2bf(acc2[mf][nf][r] + cc);
          size_t gg = (size_t)(row0 + row);
          if (col < 64) node_l[gg*64 + col] = h;
          else          node_r[gg*64 + col - 64] = h;
        }
      }
  } else {
    // ---------- rel path ----------
    int rb = g*3 + (r5 - 2);
    if (rb >= REL_BLKS) return;
    int row0 = rb * 64;
    {
      const fvec4* Rg = (const fvec4*)relE;
      #pragma unroll
      for (int it = 0; it < 16; ++it){
        int f = tid + 256*it;
        int r = f >> 6, c4 = f & 63;
        int ge = row0 + r; if (ge >= N_EDGES) ge = N_EDGES-1;
        fvec4 v = __builtin_nontemporal_load(&Rg[(size_t)ge*64 + c4]);
        uint2 u;
        u.x = pk2bf(v.x, v.y);
        u.y = pk2bf(v.z, v.w);
        int byte = (r << 9) + (c4 << 3);
        byte ^= (r & 7) << 4;
        *(uint2*)(smem + byte) = u;
      }
    }
    __syncthreads();
    f32x4 acc[4][2];
    #pragma unroll
    for (int mf = 0; mf < 4; ++mf){ acc[mf][0] = (f32x4){0.f,0.f,0.f,0.f}; acc[mf][1] = (f32x4){0.f,0.f,0.f,0.f}; }
    __builtin_amdgcn_s_setprio(1);
    for (int kb = 0; kb < 8; ++kb){
      bf16x8 a[4], b0, b1;
      #pragma unroll
      for (int mf = 0; mf < 4; ++mf){
        int row = mf*16 + (l & 15);
        int byte = (row << 9) + kb*64 + ((l >> 4) << 4);
        byte ^= (row & 7) << 4;
        a[mf] = *(const bf16x8*)(smem + byte);
      }
      b0 = *(const bf16x8*)(Wr_pk + ((size_t)(wn*8 + kb)*64 + l)*8);        // left  nb=wn
      b1 = *(const bf16x8*)(Wr_pk + ((size_t)((4+wn)*8 + kb)*64 + l)*8);    // right nb=4+wn
      #pragma unroll
      for (int mf = 0; mf < 4; ++mf){
        acc[mf][0] = __builtin_amdgcn_mfma_f32_16x16x32_bf16(a[mf], b0, acc[mf][0], 0, 0, 0);
        acc[mf][1] = __builtin_amdgcn_mfma_f32_16x16x32_bf16(a[mf], b1, acc[mf][1], 0, 0, 0);
      }
    }
    __builtin_amdgcn_s_setprio(0);
    int c = wn*16 + (l & 15);
    float cvL = cv[128 + c], cvR = cv[192 + c];
    #pragma unroll
    for (int mf = 0; mf < 4; ++mf)
      #pragma unroll
      for (int r = 0; r < 4; ++r){
        int row = mf*16 + ((l >> 4) << 2) + r;
        int e = row0 + row;
        if (e < N_EDGES)
          rel_pk[(size_t)e*64 + c] = pk2bf(acc[mf][0][r] + cvL, acc[mf][1][r] + cvR);
      }
  }
}

// ---------------- edge scoring (compose + GEMM2 + logit), barrier-free ----------------
__global__ __launch_bounds__(256, 4) void k_score(const unsigned* __restrict__ rel_pk,
    const unsigned short* __restrict__ Wc_pk, const float* __restrict__ bc,
    const unsigned short* __restrict__ node_l, const unsigned short* __restrict__ node_r,
    const unsigned* __restrict__ qctx_p,
    const int* __restrict__ src, const int* __restrict__ dst, const int* __restrict__ eg,
    float* __restrict__ exbuf, float* __restrict__ denom){
  __shared__ char smem[16384];
  int tid = threadIdx.x;
  int l = tid & 63, wn = tid >> 6;
  char* wbase = smem + wn*4096;
  char* sLc  = wbase;            // [16][64] bf16, swz (row&12)<<3  (2KB)
  char* sRin = wbase + 2048;     // [16][64] bf16, swz (row&7)<<4   (2KB)
  int e0 = blockIdx.x * 64 + wn*16;

  int idxv;
  {
    int j = l & 15;
    int e = e0 + j;
    int ec = e < N_EDGES ? e : N_EDGES-1;
    const int* p = (l < 16) ? src : (l < 32) ? dst : eg;
    idxv = p[ec];
  }
  unsigned rlrv[16];
  unsigned short nlv[16], nrv[16];
  #pragma unroll
  for (int j = 0; j < 16; ++j){
    int e = e0 + j;
    int ec = e < N_EDGES ? e : N_EDGES-1;
    rlrv[j] = rel_pk[(size_t)ec*64 + l];
    int s  = __shfl(idxv, j);
    int d2 = __shfl(idxv, 16 + j);
    nlv[j] = node_l[(size_t)s*64 + l];
    nrv[j] = node_r[(size_t)d2*64 + l];
  }
  #pragma unroll
  for (int j = 0; j < 16; ++j){
    int e = e0 + j;
    int bL = (j << 7) + (l << 1);  bL ^= (j & 12) << 3;
    int bR = (j << 7) + (l << 1);  bR ^= (j & 7) << 4;
    unsigned short lh16 = 0, rr16 = 0;
    if (e < N_EDGES){
      int b = __shfl(idxv, 32 + j);
      unsigned qv = qctx_p[b*64 + l];
      unsigned rv = rlrv[j];
      float lh = leaky(bf2f(nlv[j]) + bf2f((unsigned short)(rv & 0xFFFFu))
                       + bf2f((unsigned short)(qv & 0xFFFFu)));
      float rr = leaky(bf2f(nrv[j]) + bf2f((unsigned short)(rv >> 16))
                       + bf2f((unsigned short)(qv >> 16)));
      lh16 = f2bf(lh); rr16 = f2bf(rr);
    }
    *(unsigned short*)(sLc + bL) = lh16;
    *(unsigned short*)(sRin + bR) = rr16;
  }
  float bcv[4];
  #pragma unroll
  for (int nf = 0; nf < 4; ++nf) bcv[nf] = bc[nf*16 + (l & 15)];
  f32x4 acc2[4];
  #pragma unroll
  for (int nf = 0; nf < 4; ++nf) acc2[nf] = (f32x4){0.f,0.f,0.f,0.f};
  #pragma unroll
  for (int kb = 0; kb < 2; ++kb){
    int row = l & 15;
    int byte = (row << 7) + kb*64 + ((l >> 4) << 4);
    byte ^= (row & 7) << 4;
    bf16x8 a = *(const bf16x8*)(sRin + byte);
    #pragma unroll
    for (int nf = 0; nf < 4; ++nf){
      bf16x8 bfr = *(const bf16x8*)(Wc_pk + ((size_t)(nf*2 + kb)*64 + l)*8);
      acc2[nf] = __builtin_amdgcn_mfma_f32_16x16x32_bf16(a, bfr, acc2[nf], 0, 0, 0);
    }
  }
  int srcj[4];
  float vr[4];
  #pragma unroll
  for (int r = 0; r < 4; ++r){
    int rowl = ((l >> 4) << 2) + r;
    srcj[r] = __shfl(idxv, rowl);
    float v = 0.f;
    #pragma unroll
    for (int nf = 0; nf < 4; ++nf){
      int col = nf*16 + (l & 15);
      int byte = (rowl << 7) + (col << 1);
      byte ^= (rowl & 12) << 3;
      v += (acc2[nf][r] + bcv[nf]) * bf2f(*(unsigned short*)(sLc + byte));
    }
    v += __shfl_xor(v, 1); v += __shfl_xor(v, 2);
    v += __shfl_xor(v, 4); v += __shfl_xor(v, 8);
    vr[r] = v;
  }
  if ((l & 15) == 0){
    #pragma unroll
    for (int r = 0; r < 4; ++r){
      int rowl = ((l >> 4) << 2) + r;
      int e = e0 + rowl;
      if (e < N_EDGES){
        float ex = __expf(vr[r]);
        exbuf[e] = ex;
        atomicAdd(&denom[srcj[r]], ex);
      }
    }
  }
}

// ---------------- final pass: trans + propagate + entity aggregate ----------------
__global__ void k_passC(const float* __restrict__ exbuf, const float* __restrict__ denom,
                        const int* __restrict__ src, const int* __restrict__ dst,
                        const float* __restrict__ node_score, const int* __restrict__ ent,
                        float* __restrict__ out){
  int e = blockIdx.x*256 + threadIdx.x;
  if (e >= N_EDGES) return;
  int s = src[e];
  float tr = exbuf[e] / denom[s];
  atomicAdd(&out[ent[dst[e]]], tr * node_score[s]);
}

// ---------------- host ----------------
extern "C" void kernel_launch(void* const* d_in, const int* in_sizes, int n_in,
                              void* d_out, int out_size, void* d_ws, size_t ws_size,
                              hipStream_t stream){
  const float* mem   = (const float*)d_in[0];
  const float* nsc   = (const float*)d_in[1];
  const float* relE  = (const float*)d_in[2];
  const float* qsrc  = (const float*)d_in[3];
  const float* qrel  = (const float*)d_in[4];
  const int*   eg    = (const int*)d_in[5];
  const int*   src   = (const int*)d_in[6];
  const int*   dst   = (const int*)d_in[7];
  const int*   ent   = (const int*)d_in[8];
  const float* Wp    = (const float*)d_in[9];
  const float* bp    = (const float*)d_in[10];
  const float* Ws    = (const float*)d_in[11];
  const float* bs    = (const float*)d_in[12];
  const float* Wbs   = (const float*)d_in[13];
  const float* bbs   = (const float*)d_in[14];
  const float* Wl    = (const float*)d_in[15];
  const float* bl    = (const float*)d_in[16];
  const float* Wr    = (const float*)d_in[17];
  const float* br    = (const float*)d_in[18];
  const float* Wc    = (const float*)d_in[19];
  const float* bc    = (const float*)d_in[20];
  float* out = (float*)d_out;

  char* w = (char*)d_ws;
  auto alloc = [&](size_t bytes)->void*{
    void* p = (void*)w; w += (bytes + 255) & ~(size_t)255; return p;
  };
  unsigned short* Wbs_pk = (unsigned short*)alloc(65536*2);
  unsigned short* Wn_pk  = (unsigned short*)alloc(32768*2);
  unsigned short* Wr_pk  = (unsigned short*)alloc(32768*2);
  unsigned short* Wc_pk  = (unsigned short*)alloc(4096*2);
  float* cv  = (float*)alloc(256*4);
  unsigned* qctx_p = (unsigned*)alloc((size_t)N_Q*DSM*4);
  unsigned short* node_l = (unsigned short*)alloc((size_t)N_NODES*64*2);
  unsigned short* node_r = (unsigned short*)alloc((size_t)N_NODES*64*2);
  unsigned* rel_pk = (unsigned*)alloc((size_t)N_EDGES*64*4);
  float* exbuf  = (float*)alloc((size_t)N_EDGES*4);
  float* denom = (float*)alloc((size_t)N_NODES*4);

  k_setup<<<419, 256, 0, stream>>>(Wp, Wl, Wr, bp, cv,
                                   qsrc, Ws, bs, qrel, bl, br, qctx_p,
                                   Wbs, Wbs_pk, Wn_pk, Wr_pk, Wc, Wc_pk);
  k_proj<<<1563*5, 256, 0, stream>>>(mem, Wbs_pk, bbs, Wn_pk, cv, node_l, node_r,
                                     relE, Wr_pk, rel_pk, out, denom);
  k_score<<<(N_EDGES+63)/64, 256, 0, stream>>>(rel_pk, Wc_pk, bc, node_l, node_r, qctx_p,
                                               src, dst, eg, exbuf, denom);
  k_passC<<<(N_EDGES+255)/256, 256, 0, stream>>>(exbuf, denom, src, dst, nsc, ent, out);
}